// Round 5
// baseline (147.213 us; speedup 1.0000x reference)
//
#include <hip/hip_runtime.h>

typedef unsigned int u32;
typedef _Float16 f16;
typedef f16 f16x2 __attribute__((ext_vector_type(2)));
typedef f16 f16x4 __attribute__((ext_vector_type(4)));
typedef f16 f16x8 __attribute__((ext_vector_type(8)));
typedef float f32x4 __attribute__((ext_vector_type(4)));

#define LSEQ 900
#define BATCH 4
#define NWIN (BATCH*LSEQ)
#define WPB 2
#define NBLK (NWIN/WPB)   // 1800
#define QB 12
#define NQBLK (BATCH*LSEQ/QB)  // 300

__device__ __forceinline__ float eluf(float x){ return x > 0.f ? x : expm1f(x); }
#define BC2(u) __builtin_bit_cast(f16x2, (u))
#define ZERO8 __builtin_bit_cast(f16x8, (uint4{0,0,0,0}))

__device__ __forceinline__ f16x8 hmax8(f16x8 a, f16x8 b){
#if defined(__has_builtin) && __has_builtin(__builtin_elementwise_max)
  return __builtin_elementwise_max(a, b);
#else
  f16x8 r;
  #pragma unroll
  for (int i=0;i<8;++i) r[i] = a[i] > b[i] ? a[i] : b[i];
  return r;
#endif
}
__device__ __forceinline__ f16x4 hmax4(f16x4 a, f16x4 b){
#if defined(__has_builtin) && __has_builtin(__builtin_elementwise_max)
  return __builtin_elementwise_max(a, b);
#else
  f16x4 r;
  #pragma unroll
  for (int i=0;i<4;++i) r[i] = a[i] > b[i] ? a[i] : b[i];
  return r;
#endif
}

// ---- LDS map (u32 words) ----
#define P0U 0
#define P1U 4224
#define FEATU 7744
#define F32U 8160
#define SMTOT 8576
// f16 offsets / strides
#define T1F 0
#define T1W 4224
#define H2F 8448
#define H2W 3520
#define T2F 0
#define T2W 2496
#define H3F 8448
#define H3W 1600
#define T3F 0
#define T3W 1568
#define FEATF 15488
#define FEATW 416

// ---- ws f16 offsets ----
#define WB2A 0
#define WB2B 512
#define WB3  768
#define WB4  2304
#define WFC1 5376
#define WEND 58624
#define WC1  58624                 // C1: 4*900*80*4 f16 = 1152000
#define WTE  (WC1 + 1152000)       // TE: 1152000
#define WF32 ((WTE + 1152000)/2)   // f32 word offset: 1181312
// f32: zt @WF32, q @+144000, k @+288000, v @+432000

// ============ prep: pack all B fragments to f16 in workspace ============
__global__ __launch_bounds__(256) void prep2(
    const float* __restrict__ cw2, const float* __restrict__ cw3,
    const float* __restrict__ cw4, const float* __restrict__ fc1w,
    f16* __restrict__ wsF)
{
  const int g = blockIdx.x*256 + threadIdx.x;
  if (g >= WEND) return;
  float val;
  if (g < 512) {
    const int l = g>>3, j = g&7;
    const int oc = l&15, c = l>>4;
    const int dr = c>>1, dc = 2*(c&1) + (j>>2), ic = j&3;
    val = (oc<8 && dc<3) ? cw2[oc*36 + ic*9 + dr*3 + dc] : 0.f;
  } else if (g < 768) {
    const int u = g-512, l = u>>2, j = u&3;
    const int oc = l&15, dc = l>>4, ic = j;
    val = (oc<8 && dc<3) ? cw2[oc*36 + ic*9 + 6 + dc] : 0.f;
  } else if (g < 2304) {
    const int u = g-768, dr = u>>9, r = u&511, l = r>>3, j = r&7;
    const int oc = l&15, dc = l>>4, ic = j;
    val = (dc<3) ? cw3[oc*72 + ic*9 + dr*3 + dc] : 0.f;
  } else if (g < 5376) {
    const int u = g-2304, v = u>>9, dr = v>>1, h = v&1;
    const int r = u&511, l = r>>3, j = r&7;
    const int oc = l&15, chunk = l>>4;
    const int dcl = chunk>>1, ic = (chunk&1)*8 + j, dc = h*2 + dcl;
    val = (dc<3) ? cw4[oc*144 + ic*9 + dr*3 + dc] : 0.f;
  } else {
    const int u = g - WFC1;
    const int j = u&7, l = (u>>3)&63, st = (u>>9)%13, nt = u/(13*512);
    const int k = st*32 + (l>>4)*8 + j, n = nt*16 + (l&15);
    val = (k<400) ? fc1w[n*400 + k] : 0.f;
  }
  wsF[g] = (f16)val;
}

// ============ conv1 over the FULL sequence, once per batch ============
// C1[f] = conv3x3 SAME at frame f (full vertical context); TE[f] = same but row above = 0.
__global__ __launch_bounds__(256) void conv1full(
    const float* __restrict__ z, const float* __restrict__ cw1, const float* __restrict__ cb1,
    f16* __restrict__ C1, f16* __restrict__ TE)
{
  const int g = blockIdx.x*256 + threadIdx.x;   // 288000
  if (g >= 288000) return;
  const int c = g % 80, fb2 = g / 80, f = fb2 % 900, b = fb2 / 900;
  const float* zb = z + b*72000;
  float p[3][3];
  #pragma unroll
  for (int dr = 0; dr < 3; ++dr) {
    const int r = f + dr - 1;
    #pragma unroll
    for (int dc = 0; dc < 3; ++dc) {
      const int cc = c + dc - 1;
      p[dr][dc] = (r >= 0 && r < 900 && cc >= 0 && cc < 80) ? zb[r*80+cc] : 0.f;
    }
  }
  f16x4 cf, te;
  #pragma unroll
  for (int oc = 0; oc < 4; ++oc) {
    float accf = cb1[oc], acct = cb1[oc];
    #pragma unroll
    for (int dr = 0; dr < 3; ++dr)
      #pragma unroll
      for (int dc = 0; dc < 3; ++dc) {
        const float w = cw1[oc*9 + dr*3 + dc];
        accf += w * p[dr][dc];
        if (dr) acct += w * p[dr][dc];
      }
    cf[oc] = (f16)accf; te[oc] = (f16)acct;
  }
  *(f16x4*)(C1 + g*4) = cf;
  *(f16x4*)(TE + g*4) = te;
}

// ============ encoder: stage1 gather from C1/TE; stages 2-4 + fc1 on MFMA ============
__global__ __launch_bounds__(256,4) void encoder3(
    const f16* __restrict__ C1, const f16* __restrict__ TE,
    const float* __restrict__ toh,
    const float* __restrict__ cb2, const float* __restrict__ cb3, const float* __restrict__ cb4,
    const f16* __restrict__ wsF,
    const float* __restrict__ fc1b, const float* __restrict__ fc2w, const float* __restrict__ fc2b,
    const float* __restrict__ embw, const float* __restrict__ embb,
    const float* __restrict__ wq, const float* __restrict__ bq,
    const float* __restrict__ wk, const float* __restrict__ bk,
    const float* __restrict__ wv, const float* __restrict__ bv,
    float* __restrict__ zt_g, float* __restrict__ q_g,
    float* __restrict__ k_g, float* __restrict__ v_g)
{
  __shared__ __align__(16) u32 sm[SMTOT];
  f16* smh = (f16*)sm;
  const int tid = threadIdx.x, blk = blockIdx.x;
  const int lane = tid & 63, wid = tid >> 6;
  const int g0 = blk*WPB;
  const int b = g0/LSEQ, i0 = g0%LSEQ;

  // zero T1 + FEAT regions
  {
    const uint4 z4 = {0,0,0,0};
    uint4* p0 = (uint4*)(sm + P0U);
    for (int t = tid; t < 1056; t += 256) p0[t] = z4;
    uint4* pf = (uint4*)(sm + FEATU);
    for (int t = tid; t < 104; t += 256) pf[t] = z4;
  }
  __syncthreads();

  // ---- stage1: gather C1/TE rows + pool2x2 + elu -> T1 NHWC [24][44][4] ----
  {
    int e45[WPB], sv[WPB];
    #pragma unroll
    for (int w = 0; w < WPB; ++w) {
      const int i = i0 + w;
      e45[w] = min(i + 23, LSEQ) - 45;
      sv[w]  = max(i - 22, 0);
    }
    const f16* C1b = C1 + b*288000;
    const f16* TEb = TE + b*288000;
    for (int s = tid; s < 880; s += 256) {
      const int pr = s/40, pc = s%40;
      #pragma unroll
      for (int w = 0; w < WPB; ++w) {
        const int fa = e45[w] + 2*pr, fb = fa + 1;
        const int svw = sv[w];
        const f16* srcA = (fa == svw) ? TEb : C1b;
        const f16* srcB = (fb == svw) ? TEb : C1b;
        f16x8 va = *(const f16x8*)(srcA + (max(fa,0)*80 + 2*pc)*4);
        f16x8 vb = *(const f16x8*)(srcB + (max(fb,0)*80 + 2*pc)*4);
        if (fa < svw) va = ZERO8;
        if (fb < svw) vb = ZERO8;
        const f16x8 m8 = hmax8(va, vb);
        const f16x4 lo = __builtin_shufflevector(m8, m8, 0,1,2,3);
        const f16x4 hi = __builtin_shufflevector(m8, m8, 4,5,6,7);
        const f16x4 m4 = hmax4(lo, hi);
        f16x4 ov;
        #pragma unroll
        for (int oc = 0; oc < 4; ++oc) ov[oc] = (f16)eluf((float)m4[oc]);
        *(f16x4*)(smh + T1F + w*T1W + ((pr+1)*44 + pc+1)*4) = ov;
      }
    }
  }
  __syncthreads();

  // ---- stage2 MFMA: T1 -> conv(4->8); hmax -> H2 [22][20][8] ----
  {
    const f16x8 B2a = *(const f16x8*)(wsF + WB2A + lane*8);
    const f16x4 B2b = *(const f16x4*)(wsF + WB2B + lane*4);
    const int oc = lane&15, chunk = lane>>4;
    const float bias2 = (oc<8) ? cb2[oc] : 0.f;
    for (int t = wid; t < 110; t += 4) {
      const int mA = t*16 + oc;
      const int winA = mA/880, mmA = mA%880;
      const int r2 = mmA/40, c2 = mmA%40;
      const f16* base = smh + T1F + winA*T1W;
      const f16* pA = base + ((r2 + (chunk>>1))*44 + c2 + 2*(chunk&1))*4;
      const f16x4 lo = *(const f16x4*)(pA);
      const f16x4 hi = *(const f16x4*)(pA + 4);
      const f16x8 a8 = __builtin_shufflevector(lo, hi, 0,1,2,3,4,5,6,7);
      f32x4 acc = {bias2, bias2, bias2, bias2};
      acc = __builtin_amdgcn_mfma_f32_16x16x32_f16(a8, B2a, acc, 0, 0, 0);
      const f16x4 a4 = *(const f16x4*)(base + ((r2+2)*44 + c2 + chunk)*4);
      acc = __builtin_amdgcn_mfma_f32_16x16x16f16(a4, B2b, acc, 0, 0, 0);
      if (oc < 8) {
        #pragma unroll
        for (int p = 0; p < 2; ++p) {
          const int mE = t*16 + chunk*4 + 2*p;
          const int winE = mE/880, mmE = mE%880;
          const int rE = mmE/40, cE = mmE%40;
          smh[H2F + winE*H2W + (rE*20 + (cE>>1))*8 + oc] = (f16)fmaxf(acc[2*p], acc[2*p+1]);
        }
      }
    }
  }
  __syncthreads();

  // ---- vertical max + elu: H2 -> T2 NHWC [13][24][8]; zero T2 border ----
  {
    for (int s = tid; s < 624; s += 256) {
      const int win = s/312, id = s%312;
      const int r = id/24, c = id%24;
      if (!(r>=1 && r<=11 && c>=1 && c<=20)) {
        const uint4 z4 = {0,0,0,0};
        *(uint4*)(smh + T2F + win*T2W + (r*24+c)*8) = z4;
      }
    }
    for (int s = tid; s < 1760; s += 256) {
      const int win = s/880, u = s%880;
      const int pr = u/80, rem = u%80, cp = rem/4, op = rem%4;
      const u32* h2 = (const u32*)(smh + H2F + win*H2W);
      const u32 a  = h2[((2*pr  )*20 + cp)*4 + op];
      const u32 b2 = h2[((2*pr+1)*20 + cp)*4 + op];
      const f16x2 av = BC2(a), bv = BC2(b2);
      f16x2 o;
      o.x = (f16)eluf(fmaxf((float)av.x, (float)bv.x));
      o.y = (f16)eluf(fmaxf((float)av.y, (float)bv.y));
      ((u32*)(smh + T2F + win*T2W))[((pr+1)*24 + cp+1)*4 + op] = __builtin_bit_cast(u32, o);
    }
  }
  __syncthreads();

  // ---- stage3 MFMA: T2 -> conv(8->16); hmax -> H3 [10][10][16] ----
  {
    f16x8 B3r[3];
    #pragma unroll
    for (int dr = 0; dr < 3; ++dr) B3r[dr] = *(const f16x8*)(wsF + WB3 + dr*512 + lane*8);
    const int oc = lane&15, chunk = lane>>4;
    const float bias3 = cb3[oc];
    for (int t = wid; t < 28; t += 4) {
      const int mA = t*16 + oc;
      const int winA = mA/220, mmA = mA%220;
      const int r3 = mmA/20, c3 = mmA%20;
      const f16* base = smh + T2F + min(winA,1)*T2W;
      f32x4 acc = {bias3, bias3, bias3, bias3};
      #pragma unroll
      for (int dr = 0; dr < 3; ++dr) {
        const f16x8 a8 = *(const f16x8*)(base + ((r3+dr)*24 + c3 + chunk)*8);
        acc = __builtin_amdgcn_mfma_f32_16x16x32_f16(a8, B3r[dr], acc, 0, 0, 0);
      }
      #pragma unroll
      for (int p = 0; p < 2; ++p) {
        const int mE = t*16 + chunk*4 + 2*p;
        if (mE < 440) {
          const int winE = mE/220, mmE = mE%220;
          const int rE = mmE/20, cE = mmE%20;
          if (rE < 10)
            smh[H3F + winE*H3W + (rE*10 + (cE>>1))*16 + oc] = (f16)fmaxf(acc[2*p], acc[2*p+1]);
        }
      }
    }
  }
  __syncthreads();

  // ---- vertical max + elu: H3 -> T3 NHWC [7][14][16]; zero T3 border ----
  {
    for (int s = tid; s < 196; s += 256) {
      const int win = s/98, id = s%98;
      const int r = id/14, c = id%14;
      if (!(r>=1 && r<=5 && c>=1 && c<=10)) {
        const uint4 z4 = {0,0,0,0};
        *(uint4*)(smh + T3F + win*T3W + (r*14+c)*16)     = z4;
        *(uint4*)(smh + T3F + win*T3W + (r*14+c)*16 + 8) = z4;
      }
    }
    for (int s = tid; s < 800; s += 256) {
      const int win = s/400, u = s%400;
      const int pr = u/80, rem = u%80, cp = rem/8, op = rem%8;
      const u32* h3 = (const u32*)(smh + H3F + win*H3W);
      const u32 a  = h3[((2*pr  )*10 + cp)*8 + op];
      const u32 b2 = h3[((2*pr+1)*10 + cp)*8 + op];
      const f16x2 av = BC2(a), bv = BC2(b2);
      f16x2 o;
      o.x = (f16)eluf(fmaxf((float)av.x, (float)bv.x));
      o.y = (f16)eluf(fmaxf((float)av.y, (float)bv.y));
      ((u32*)(smh + T3F + win*T3W))[((pr+1)*14 + cp+1)*8 + op] = __builtin_bit_cast(u32, o);
    }
  }
  __syncthreads();

  // ---- stage4 MFMA: T3 -> conv(16->16) + pool1x2 + elu -> feat NCHW f16[400] ----
  {
    f16x8 B4r[6];
    #pragma unroll
    for (int v = 0; v < 6; ++v) B4r[v] = *(const f16x8*)(wsF + WB4 + v*512 + lane*8);
    const int oc = lane&15, chunk = lane>>4;
    const int dcl = chunk>>1, hsel = chunk&1;
    const float bias4 = cb4[oc];
    for (int t = wid; t < 7; t += 4) {
      const int mA = t*16 + oc;
      const int winA = mA/50, mmA = mA%50;
      const int r4 = mmA/10, c4 = mmA%10;
      const f16* base = smh + T3F + min(winA,1)*T3W;
      f32x4 acc = {bias4, bias4, bias4, bias4};
      #pragma unroll
      for (int v = 0; v < 6; ++v) {
        const int dr = v>>1, h = v&1;
        const f16x8 a8 = *(const f16x8*)(base + ((r4+dr)*14 + c4 + h*2 + dcl)*16 + hsel*8);
        acc = __builtin_amdgcn_mfma_f32_16x16x32_f16(a8, B4r[v], acc, 0, 0, 0);
      }
      #pragma unroll
      for (int p = 0; p < 2; ++p) {
        const int mE = t*16 + chunk*4 + 2*p;
        if (mE < 100) {
          const int winE = mE/50, mmE = mE%50;
          const int rE = mmE/10, cE = mmE%10;
          smh[FEATF + winE*FEATW + oc*25 + rE*5 + (cE>>1)] = (f16)eluf(fmaxf(acc[2*p], acc[2*p+1]));
        }
      }
    }
  }
  __syncthreads();

  // ---- fc1 MFMA: feat[2x416] x fc1B -> h1 f32 [2][128], elu ----
  {
    const int col = lane&15, kg = lane>>4;
    const int winc = min(col, 1);
    float* h1 = (float*)(sm + F32U);
    #pragma unroll
    for (int q2 = 0; q2 < 2; ++q2) {
      const int nt = wid + q2*4;
      f32x4 acc = {0.f, 0.f, 0.f, 0.f};
      for (int st = 0; st < 13; ++st) {
        const f16x8 a8 = *(const f16x8*)(smh + FEATF + winc*FEATW + st*32 + kg*8);
        const f16x8 b8 = *(const f16x8*)(wsF + WFC1 + ((nt*13 + st)*64 + lane)*8);
        acc = __builtin_amdgcn_mfma_f32_16x16x32_f16(a8, b8, acc, 0, 0, 0);
      }
      if (lane < 16) {
        const int n = nt*16 + col;
        const float fb = fc1b[n];
        h1[0*128 + n] = eluf(acc[0] + fb);
        h1[1*128 + n] = eluf(acc[1] + fb);
      }
    }
  }
  __syncthreads();

  // ---- fc2 -> emb -> qkv ----
  float* fregion = (float*)(sm + F32U);
  float* h1f = fregion;
  float* zpf = fregion + 256;
  float* ztf = fregion + 336;
  if (tid < 80) {
    const int w = tid/40, n = tid%40;
    const float4* hv = (const float4*)(h1f + w*128);
    const float4* wr = (const float4*)(fc2w + n*128);
    float acc = fc2b[n];
    #pragma unroll 8
    for (int c = 0; c < 32; ++c) {
      const float4 a = wr[c], x = hv[c];
      acc += a.x*x.x + a.y*x.y + a.z*x.z + a.w*x.w;
    }
    zpf[w*40 + n] = acc;
  }
  __syncthreads();
  if (tid < 80) {
    const int w = tid/40, n = tid%40;
    const float* zp = zpf + w*40;
    const float* wr = embw + n*45;
    float acc = embb[n];
    #pragma unroll 8
    for (int j = 0; j < 40; ++j) acc += wr[j]*zp[j];
    #pragma unroll
    for (int j = 0; j < 5; ++j)  acc += wr[40+j]*toh[b*5 + j];
    const float v2 = eluf(acc);
    ztf[w*40 + n] = v2;
    zt_g[(b*LSEQ + i0 + w)*40 + n] = v2;
  }
  __syncthreads();
  if (tid < 240) {
    const int which = tid/80, r = tid%80, w = r/40, n = r%40;
    const float* wm = which==0 ? wq : (which==1 ? wk : wv);
    const float* bb = which==0 ? bq : (which==1 ? bk : bv);
    const float4* wr = (const float4*)(wm + n*40);
    const float4* zv = (const float4*)(ztf + w*40);
    float acc = bb[n];
    #pragma unroll
    for (int c = 0; c < 10; ++c) {
      const float4 a = wr[c], x = zv[c];
      acc += a.x*x.x + a.y*x.y + a.z*x.z + a.w*x.w;
    }
    float* dst = which==0 ? q_g : (which==1 ? k_g : v_g);
    dst[(b*LSEQ + i0 + w)*40 + n] = acc;
  }
}

// ============ Q-tiled attention: QB rows/block share K,V reads ============
__global__ __launch_bounds__(256) void attn2(
    const float* __restrict__ q_g, const float* __restrict__ k_g,
    const float* __restrict__ v_g, const float* __restrict__ zt_g,
    const int* __restrict__ dur,
    const float* __restrict__ flw1, const float* __restrict__ flb1,
    const float* __restrict__ flw2, const float* __restrict__ flb2,
    const float* __restrict__ stw1, const float* __restrict__ stb1,
    const float* __restrict__ stw2, const float* __restrict__ stb2,
    const float* __restrict__ edw1, const float* __restrict__ edb1,
    const float* __restrict__ edw2, const float* __restrict__ edb2,
    float* __restrict__ out)
{
  __shared__ __align__(16) float sq[QB][40];
  __shared__ __align__(16) float szt[QB][40];
  __shared__ __align__(16) float ses[QB][900];
  __shared__ float smx[QB];
  __shared__ float spart[QB][16];
  __shared__ float sden[QB];
  __shared__ __align__(16) float spv[QB][2][40];
  __shared__ __align__(16) float xr[QB][40];
  __shared__ float hb[QB][30];

  const int tid = threadIdx.x;
  const int blk = blockIdx.x;
  const int b = blk / (LSEQ/QB);
  const int q0 = (blk % (LSEQ/QB)) * QB;
  const int durb = dur[b];

  for (int t = tid; t < QB*40*2; t += 256) {
    const int which = t / (QB*40), r = t % (QB*40);
    const int q = r/40, d = r%40;
    const float v = (which ? zt_g : q_g)[(b*LSEQ + q0 + q)*40 + d];
    if (which) szt[q][d] = v; else sq[q][d] = v;
  }
  __syncthreads();

  const float scale = 0.15811388300841897f;   // 1/sqrt(40)
  for (int m = tid; m < LSEQ; m += 256) {
    if (m < durb) {
      float4 kv[10];
      const float4* kr4 = (const float4*)(k_g + (b*LSEQ+m)*40);
      #pragma unroll
      for (int j = 0; j < 10; ++j) kv[j] = kr4[j];
      #pragma unroll
      for (int q = 0; q < QB; ++q) {
        float s = -1e-12f;
        if (q0 + q < durb) {
          const float4* qv = (const float4*)(&sq[q][0]);
          float acc = 0.f;
          #pragma unroll
          for (int j = 0; j < 10; ++j) {
            const float4 a = kv[j], x = qv[j];
            acc += a.x*x.x + a.y*x.y + a.z*x.z + a.w*x.w;
          }
          s = acc*scale;
        }
        ses[q][m] = s;
      }
    } else {
      #pragma unroll
      for (int q = 0; q < QB; ++q) ses[q][m] = -1e-12f;
    }
  }
  __syncthreads();

  // per-row max: wave w handles rows 3w..3w+2
  {
    const int lane = tid & 63, w = tid >> 6;
    #pragma unroll
    for (int r = 0; r < 3; ++r) {
      const int row = w*3 + r;
      float mx = -3.4e38f;
      for (int m = lane; m < LSEQ; m += 64) mx = fmaxf(mx, ses[row][m]);
      #pragma unroll
      for (int off = 32; off > 0; off >>= 1) mx = fmaxf(mx, __shfl_xor(mx, off));
      if (lane == 0) smx[row] = mx;
    }
  }
  __syncthreads();

  // exp + partial sums
  if (tid < QB*16) {
    const int q = tid >> 4, c = tid & 15;
    const float mx = smx[q];
    const int m0 = c*57, m1 = min(m0+57, LSEQ);
    float s = 0.f;
    for (int m = m0; m < m1; ++m) { const float e = expf(ses[q][m]-mx); ses[q][m] = e; s += e; }
    spart[q][c] = s;
  }
  __syncthreads();
  if (tid < QB) {
    float s = 0.f;
    #pragma unroll
    for (int c = 0; c < 16; ++c) s += spart[tid][c];
    sden[tid] = s;
  }
  __syncthreads();

  // PV: thread (q, dq, half)
  if (tid < QB*20) {
    const int q = tid/20, r = tid%20, dq = r>>1, h = r&1;
    const int m0 = h*450;
    float4 acc = {0.f,0.f,0.f,0.f};
    const float4* vr = (const float4*)(v_g + (b*LSEQ+m0)*40 + dq*4);
    const float* er = &ses[q][m0];
    for (int m = 0; m < 450; ++m) {
      const float e = er[m];
      const float4 v = vr[m*10];
      acc.x += e*v.x; acc.y += e*v.y; acc.z += e*v.z; acc.w += e*v.w;
    }
    *(float4*)(&spv[q][h][dq*4]) = acc;
  }
  __syncthreads();
  if (tid < QB*10) {
    const int q = tid/10, dq = tid%10;
    const float rden = 1.f/sden[q];
    const float4 a = *(const float4*)(&spv[q][0][dq*4]);
    const float4 c = *(const float4*)(&spv[q][1][dq*4]);
    const float4 zt4 = *(const float4*)(&szt[q][dq*4]);
    float4 o;
    o.x = (a.x+c.x)*rden + zt4.x; o.y = (a.y+c.y)*rden + zt4.y;
    o.z = (a.z+c.z)*rden + zt4.z; o.w = (a.w+c.w)*rden + zt4.w;
    *(float4*)(&xr[q][dq*4]) = o;
  }
  __syncthreads();

  // heads: 40 -> 10 (elu)
  for (int s = tid; s < QB*30; s += 256) {
    const int q = s/30, rr = s%30, hd = rr/10, j = rr%10;
    const float* w1 = hd==0?flw1:(hd==1?stw1:edw1);
    const float* b1 = hd==0?flb1:(hd==1?stb1:edb1);
    float a = b1[j];
    #pragma unroll 8
    for (int d = 0; d < 40; ++d) a += w1[j*40+d]*xr[q][d];
    hb[q][hd*10+j] = eluf(a);
  }
  __syncthreads();
  if (tid < QB*3) {
    const int q = tid/3, hd = tid%3;
    const float* w2 = hd==0?flw2:(hd==1?stw2:edw2);
    const float* b2 = hd==0?flb2:(hd==1?stb2:edb2);
    float a = b2[0];
    #pragma unroll
    for (int j = 0; j < 10; ++j) a += w2[j]*hb[q][hd*10+j];
    out[hd*NWIN + b*LSEQ + q0 + q] = a;
  }
}

extern "C" void kernel_launch(void* const* d_in, const int* in_sizes, int n_in,
                              void* d_out, int out_size, void* d_ws, size_t ws_size,
                              hipStream_t stream) {
  const float* z    = (const float*)d_in[0];
  const float* toh  = (const float*)d_in[1];
  const int*   dur  = (const int*)d_in[2];
  const float* cw1  = (const float*)d_in[3];
  const float* cb1  = (const float*)d_in[4];
  const float* cw2  = (const float*)d_in[5];
  const float* cb2  = (const float*)d_in[6];
  const float* cw3  = (const float*)d_in[7];
  const float* cb3  = (const float*)d_in[8];
  const float* cw4  = (const float*)d_in[9];
  const float* cb4  = (const float*)d_in[10];
  const float* fc1w = (const float*)d_in[11];
  const float* fc1b = (const float*)d_in[12];
  const float* fc2w = (const float*)d_in[13];
  const float* fc2b = (const float*)d_in[14];
  const float* embw = (const float*)d_in[15];
  const float* embb = (const float*)d_in[16];
  const float* wq   = (const float*)d_in[17];
  const float* bq   = (const float*)d_in[18];
  const float* wk   = (const float*)d_in[19];
  const float* bk   = (const float*)d_in[20];
  const float* wv   = (const float*)d_in[21];
  const float* bv   = (const float*)d_in[22];
  const float* flw1 = (const float*)d_in[23];
  const float* flb1 = (const float*)d_in[24];
  const float* flw2 = (const float*)d_in[25];
  const float* flb2 = (const float*)d_in[26];
  const float* stw1 = (const float*)d_in[27];
  const float* stb1 = (const float*)d_in[28];
  const float* stw2 = (const float*)d_in[29];
  const float* stb2 = (const float*)d_in[30];
  const float* edw1 = (const float*)d_in[31];
  const float* edb1 = (const float*)d_in[32];
  const float* edw2 = (const float*)d_in[33];
  const float* edb2 = (const float*)d_in[34];

  f16*   wsF = (f16*)d_ws;
  f16*   C1  = wsF + WC1;
  f16*   TE  = wsF + WTE;
  float* wsf = (float*)d_ws;
  float* zt = wsf + WF32;
  float* q  = wsf + WF32 + 144000;
  float* k  = wsf + WF32 + 288000;
  float* v  = wsf + WF32 + 432000;

  prep2<<<(WEND+255)/256, 256, 0, stream>>>(cw2, cw3, cw4, fc1w, wsF);
  conv1full<<<(288000+255)/256, 256, 0, stream>>>(z, cw1, cb1, C1, TE);
  encoder3<<<NBLK, 256, 0, stream>>>(C1, TE, toh, cb2, cb3, cb4, wsF,
                                     fc1b, fc2w, fc2b, embw, embb,
                                     wq, bq, wk, bk, wv, bv, zt, q, k, v);
  attn2<<<NQBLK, 256, 0, stream>>>(q, k, v, zt, dur,
                                   flw1, flb1, flw2, flb2,
                                   stw1, stb1, stw2, stb2,
                                   edw1, edb1, edw2, edb2,
                                   (float*)d_out);
}

// Round 6
// 118.719 us; speedup vs baseline: 1.2400x; 1.2400x over previous
//
#include <hip/hip_runtime.h>

typedef unsigned int u32;
typedef _Float16 f16;
typedef f16 f16x2 __attribute__((ext_vector_type(2)));
typedef f16 f16x4 __attribute__((ext_vector_type(4)));
typedef f16 f16x8 __attribute__((ext_vector_type(8)));
typedef float f32x4 __attribute__((ext_vector_type(4)));

#define LSEQ 900
#define BATCH 4
#define NWIN (BATCH*LSEQ)
#define WPB 2
#define NBLK (NWIN/WPB)   // 1800

__device__ __forceinline__ float eluf(float x){ return x > 0.f ? x : expm1f(x); }
#define BC2(u) __builtin_bit_cast(f16x2, (u))
#define ZERO8 __builtin_bit_cast(f16x8, (uint4{0,0,0,0}))

__device__ __forceinline__ f16x8 hmax8(f16x8 a, f16x8 b){
#if defined(__has_builtin) && __has_builtin(__builtin_elementwise_max)
  return __builtin_elementwise_max(a, b);
#else
  f16x8 r;
  #pragma unroll
  for (int i=0;i<8;++i) r[i] = a[i] > b[i] ? a[i] : b[i];
  return r;
#endif
}
__device__ __forceinline__ f16x4 hmax4(f16x4 a, f16x4 b){
#if defined(__has_builtin) && __has_builtin(__builtin_elementwise_max)
  return __builtin_elementwise_max(a, b);
#else
  f16x4 r;
  #pragma unroll
  for (int i=0;i<4;++i) r[i] = a[i] > b[i] ? a[i] : b[i];
  return r;
#endif
}

// ---- LDS map (u32 words) ----
#define P0U 0
#define P1U 4224
#define FEATU 7744
#define F32U 8160
#define SMTOT 8576
// f16 offsets / strides
#define T1F 0
#define T1W 4224
#define H2F 8448
#define H2W 3520
#define T2F 0
#define T2W 2496
#define H3F 8448
#define H3W 1600
#define T3F 0
#define T3W 1568
#define FEATF 15488
#define FEATW 416

// ---- ws f16 offsets ----
#define WB2A 0
#define WB2B 512
#define WB3  768
#define WB4  2304
#define WFC1 5376
#define WEND 58624
#define WC1  58624                 // C1: 4*900*80*4 f16 = 1152000
#define WTE  (WC1 + 1152000)       // TE: 1152000
#define WF32 ((WTE + 1152000)/2)   // f32 word offset: 1181312
// f32: zt @WF32, q @+144000, k @+288000, v @+432000

#define PREP_BLOCKS ((WEND+255)/256)        // 229
#define CONV_BLOCKS ((288000+255)/256)      // 1125

// ============ fused prep: weight packing (blocks < PREP_BLOCKS) + full-seq conv1 ============
__global__ __launch_bounds__(256) void prep_all(
    const float* __restrict__ z,
    const float* __restrict__ cw1, const float* __restrict__ cb1,
    const float* __restrict__ cw2, const float* __restrict__ cw3,
    const float* __restrict__ cw4, const float* __restrict__ fc1w,
    f16* __restrict__ wsF, f16* __restrict__ C1, f16* __restrict__ TE)
{
  const int blk = blockIdx.x;
  if (blk < PREP_BLOCKS) {
    const int g = blk*256 + threadIdx.x;
    if (g >= WEND) return;
    float val;
    if (g < 512) {
      const int l = g>>3, j = g&7;
      const int oc = l&15, c = l>>4;
      const int dr = c>>1, dc = 2*(c&1) + (j>>2), ic = j&3;
      val = (oc<8 && dc<3) ? cw2[oc*36 + ic*9 + dr*3 + dc] : 0.f;
    } else if (g < 768) {
      const int u = g-512, l = u>>2, j = u&3;
      const int oc = l&15, dc = l>>4, ic = j;
      val = (oc<8 && dc<3) ? cw2[oc*36 + ic*9 + 6 + dc] : 0.f;
    } else if (g < 2304) {
      const int u = g-768, dr = u>>9, r = u&511, l = r>>3, j = r&7;
      const int oc = l&15, dc = l>>4, ic = j;
      val = (dc<3) ? cw3[oc*72 + ic*9 + dr*3 + dc] : 0.f;
    } else if (g < 5376) {
      const int u = g-2304, v = u>>9, dr = v>>1, h = v&1;
      const int r = u&511, l = r>>3, j = r&7;
      const int oc = l&15, chunk = l>>4;
      const int dcl = chunk>>1, ic = (chunk&1)*8 + j, dc = h*2 + dcl;
      val = (dc<3) ? cw4[oc*144 + ic*9 + dr*3 + dc] : 0.f;
    } else {
      const int u = g - WFC1;
      const int j = u&7, l = (u>>3)&63, st = (u>>9)%13, nt = u/(13*512);
      const int k = st*32 + (l>>4)*8 + j, n = nt*16 + (l&15);
      val = (k<400) ? fc1w[n*400 + k] : 0.f;
    }
    wsF[g] = (f16)val;
  } else {
    const int g = (blk - PREP_BLOCKS)*256 + threadIdx.x;   // 0..287999
    if (g >= 288000) return;
    const int c = g % 80, fb2 = g / 80, f = fb2 % 900, b = fb2 / 900;
    const float* zb = z + b*72000;
    float p[3][3];
    #pragma unroll
    for (int dr = 0; dr < 3; ++dr) {
      const int r = f + dr - 1;
      #pragma unroll
      for (int dc = 0; dc < 3; ++dc) {
        const int cc = c + dc - 1;
        p[dr][dc] = (r >= 0 && r < 900 && cc >= 0 && cc < 80) ? zb[r*80+cc] : 0.f;
      }
    }
    f16x4 cf, te;
    #pragma unroll
    for (int oc = 0; oc < 4; ++oc) {
      float accf = cb1[oc], acct = cb1[oc];
      #pragma unroll
      for (int dr = 0; dr < 3; ++dr)
        #pragma unroll
        for (int dc = 0; dc < 3; ++dc) {
          const float w = cw1[oc*9 + dr*3 + dc];
          accf += w * p[dr][dc];
          if (dr) acct += w * p[dr][dc];
        }
      cf[oc] = (f16)accf; te[oc] = (f16)acct;
    }
    *(f16x4*)(C1 + g*4) = cf;
    *(f16x4*)(TE + g*4) = te;
  }
}

// ============ encoder: stage1 gather from C1/TE; stages 2-4 + fc1 on MFMA ============
__global__ __launch_bounds__(256,4) void encoder3(
    const f16* __restrict__ C1, const f16* __restrict__ TE,
    const float* __restrict__ toh,
    const float* __restrict__ cb2, const float* __restrict__ cb3, const float* __restrict__ cb4,
    const f16* __restrict__ wsF,
    const float* __restrict__ fc1b, const float* __restrict__ fc2w, const float* __restrict__ fc2b,
    const float* __restrict__ embw, const float* __restrict__ embb,
    const float* __restrict__ wq, const float* __restrict__ bq,
    const float* __restrict__ wk, const float* __restrict__ bk,
    const float* __restrict__ wv, const float* __restrict__ bv,
    float* __restrict__ zt_g, float* __restrict__ q_g,
    float* __restrict__ k_g, float* __restrict__ v_g)
{
  __shared__ __align__(16) u32 sm[SMTOT];
  f16* smh = (f16*)sm;
  const int tid = threadIdx.x, blk = blockIdx.x;
  const int lane = tid & 63, wid = tid >> 6;
  const int g0 = blk*WPB;
  const int b = g0/LSEQ, i0 = g0%LSEQ;

  // zero T1 + FEAT regions
  {
    const uint4 z4 = {0,0,0,0};
    uint4* p0 = (uint4*)(sm + P0U);
    for (int t = tid; t < 1056; t += 256) p0[t] = z4;
    uint4* pf = (uint4*)(sm + FEATU);
    for (int t = tid; t < 104; t += 256) pf[t] = z4;
  }
  __syncthreads();

  // ---- stage1: gather C1/TE rows + pool2x2 + elu -> T1 NHWC [24][44][4] ----
  {
    int e45[WPB], sv[WPB];
    #pragma unroll
    for (int w = 0; w < WPB; ++w) {
      const int i = i0 + w;
      e45[w] = min(i + 23, LSEQ) - 45;
      sv[w]  = max(i - 22, 0);
    }
    const f16* C1b = C1 + b*288000;
    const f16* TEb = TE + b*288000;
    for (int s = tid; s < 880; s += 256) {
      const int pr = s/40, pc = s%40;
      #pragma unroll
      for (int w = 0; w < WPB; ++w) {
        const int fa = e45[w] + 2*pr, fb = fa + 1;
        const int svw = sv[w];
        const f16* srcA = (fa == svw) ? TEb : C1b;
        const f16* srcB = (fb == svw) ? TEb : C1b;
        f16x8 va = *(const f16x8*)(srcA + (max(fa,0)*80 + 2*pc)*4);
        f16x8 vb = *(const f16x8*)(srcB + (max(fb,0)*80 + 2*pc)*4);
        if (fa < svw) va = ZERO8;
        if (fb < svw) vb = ZERO8;
        const f16x8 m8 = hmax8(va, vb);
        const f16x4 lo = __builtin_shufflevector(m8, m8, 0,1,2,3);
        const f16x4 hi = __builtin_shufflevector(m8, m8, 4,5,6,7);
        const f16x4 m4 = hmax4(lo, hi);
        f16x4 ov;
        #pragma unroll
        for (int oc = 0; oc < 4; ++oc) ov[oc] = (f16)eluf((float)m4[oc]);
        *(f16x4*)(smh + T1F + w*T1W + ((pr+1)*44 + pc+1)*4) = ov;
      }
    }
  }
  __syncthreads();

  // ---- stage2 MFMA: T1 -> conv(4->8); hmax -> H2 [22][20][8] ----
  {
    const f16x8 B2a = *(const f16x8*)(wsF + WB2A + lane*8);
    const f16x4 B2b = *(const f16x4*)(wsF + WB2B + lane*4);
    const int oc = lane&15, chunk = lane>>4;
    const float bias2 = (oc<8) ? cb2[oc] : 0.f;
    for (int t = wid; t < 110; t += 4) {
      const int mA = t*16 + oc;
      const int winA = mA/880, mmA = mA%880;
      const int r2 = mmA/40, c2 = mmA%40;
      const f16* base = smh + T1F + winA*T1W;
      const f16* pA = base + ((r2 + (chunk>>1))*44 + c2 + 2*(chunk&1))*4;
      const f16x4 lo = *(const f16x4*)(pA);
      const f16x4 hi = *(const f16x4*)(pA + 4);
      const f16x8 a8 = __builtin_shufflevector(lo, hi, 0,1,2,3,4,5,6,7);
      f32x4 acc = {bias2, bias2, bias2, bias2};
      acc = __builtin_amdgcn_mfma_f32_16x16x32_f16(a8, B2a, acc, 0, 0, 0);
      const f16x4 a4 = *(const f16x4*)(base + ((r2+2)*44 + c2 + chunk)*4);
      acc = __builtin_amdgcn_mfma_f32_16x16x16f16(a4, B2b, acc, 0, 0, 0);
      if (oc < 8) {
        #pragma unroll
        for (int p = 0; p < 2; ++p) {
          const int mE = t*16 + chunk*4 + 2*p;
          const int winE = mE/880, mmE = mE%880;
          const int rE = mmE/40, cE = mmE%40;
          smh[H2F + winE*H2W + (rE*20 + (cE>>1))*8 + oc] = (f16)fmaxf(acc[2*p], acc[2*p+1]);
        }
      }
    }
  }
  __syncthreads();

  // ---- vertical max + elu: H2 -> T2 NHWC [13][24][8]; zero T2 border ----
  {
    for (int s = tid; s < 624; s += 256) {
      const int win = s/312, id = s%312;
      const int r = id/24, c = id%24;
      if (!(r>=1 && r<=11 && c>=1 && c<=20)) {
        const uint4 z4 = {0,0,0,0};
        *(uint4*)(smh + T2F + win*T2W + (r*24+c)*8) = z4;
      }
    }
    for (int s = tid; s < 1760; s += 256) {
      const int win = s/880, u = s%880;
      const int pr = u/80, rem = u%80, cp = rem/4, op = rem%4;
      const u32* h2 = (const u32*)(smh + H2F + win*H2W);
      const u32 a  = h2[((2*pr  )*20 + cp)*4 + op];
      const u32 b2 = h2[((2*pr+1)*20 + cp)*4 + op];
      const f16x2 av = BC2(a), bv = BC2(b2);
      f16x2 o;
      o.x = (f16)eluf(fmaxf((float)av.x, (float)bv.x));
      o.y = (f16)eluf(fmaxf((float)av.y, (float)bv.y));
      ((u32*)(smh + T2F + win*T2W))[((pr+1)*24 + cp+1)*4 + op] = __builtin_bit_cast(u32, o);
    }
  }
  __syncthreads();

  // ---- stage3 MFMA: T2 -> conv(8->16); hmax -> H3 [10][10][16] ----
  {
    f16x8 B3r[3];
    #pragma unroll
    for (int dr = 0; dr < 3; ++dr) B3r[dr] = *(const f16x8*)(wsF + WB3 + dr*512 + lane*8);
    const int oc = lane&15, chunk = lane>>4;
    const float bias3 = cb3[oc];
    for (int t = wid; t < 28; t += 4) {
      const int mA = t*16 + oc;
      const int winA = mA/220, mmA = mA%220;
      const int r3 = mmA/20, c3 = mmA%20;
      const f16* base = smh + T2F + min(winA,1)*T2W;
      f32x4 acc = {bias3, bias3, bias3, bias3};
      #pragma unroll
      for (int dr = 0; dr < 3; ++dr) {
        const f16x8 a8 = *(const f16x8*)(base + ((r3+dr)*24 + c3 + chunk)*8);
        acc = __builtin_amdgcn_mfma_f32_16x16x32_f16(a8, B3r[dr], acc, 0, 0, 0);
      }
      #pragma unroll
      for (int p = 0; p < 2; ++p) {
        const int mE = t*16 + chunk*4 + 2*p;
        if (mE < 440) {
          const int winE = mE/220, mmE = mE%220;
          const int rE = mmE/20, cE = mmE%20;
          if (rE < 10)
            smh[H3F + winE*H3W + (rE*10 + (cE>>1))*16 + oc] = (f16)fmaxf(acc[2*p], acc[2*p+1]);
        }
      }
    }
  }
  __syncthreads();

  // ---- vertical max + elu: H3 -> T3 NHWC [7][14][16]; zero T3 border ----
  {
    for (int s = tid; s < 196; s += 256) {
      const int win = s/98, id = s%98;
      const int r = id/14, c = id%14;
      if (!(r>=1 && r<=5 && c>=1 && c<=10)) {
        const uint4 z4 = {0,0,0,0};
        *(uint4*)(smh + T3F + win*T3W + (r*14+c)*16)     = z4;
        *(uint4*)(smh + T3F + win*T3W + (r*14+c)*16 + 8) = z4;
      }
    }
    for (int s = tid; s < 800; s += 256) {
      const int win = s/400, u = s%400;
      const int pr = u/80, rem = u%80, cp = rem/8, op = rem%8;
      const u32* h3 = (const u32*)(smh + H3F + win*H3W);
      const u32 a  = h3[((2*pr  )*10 + cp)*8 + op];
      const u32 b2 = h3[((2*pr+1)*10 + cp)*8 + op];
      const f16x2 av = BC2(a), bv = BC2(b2);
      f16x2 o;
      o.x = (f16)eluf(fmaxf((float)av.x, (float)bv.x));
      o.y = (f16)eluf(fmaxf((float)av.y, (float)bv.y));
      ((u32*)(smh + T3F + win*T3W))[((pr+1)*14 + cp+1)*8 + op] = __builtin_bit_cast(u32, o);
    }
  }
  __syncthreads();

  // ---- stage4 MFMA: T3 -> conv(16->16) + pool1x2 + elu -> feat NCHW f16[400] ----
  {
    f16x8 B4r[6];
    #pragma unroll
    for (int v = 0; v < 6; ++v) B4r[v] = *(const f16x8*)(wsF + WB4 + v*512 + lane*8);
    const int oc = lane&15, chunk = lane>>4;
    const int dcl = chunk>>1, hsel = chunk&1;
    const float bias4 = cb4[oc];
    for (int t = wid; t < 7; t += 4) {
      const int mA = t*16 + oc;
      const int winA = mA/50, mmA = mA%50;
      const int r4 = mmA/10, c4 = mmA%10;
      const f16* base = smh + T3F + min(winA,1)*T3W;
      f32x4 acc = {bias4, bias4, bias4, bias4};
      #pragma unroll
      for (int v = 0; v < 6; ++v) {
        const int dr = v>>1, h = v&1;
        const f16x8 a8 = *(const f16x8*)(base + ((r4+dr)*14 + c4 + h*2 + dcl)*16 + hsel*8);
        acc = __builtin_amdgcn_mfma_f32_16x16x32_f16(a8, B4r[v], acc, 0, 0, 0);
      }
      #pragma unroll
      for (int p = 0; p < 2; ++p) {
        const int mE = t*16 + chunk*4 + 2*p;
        if (mE < 100) {
          const int winE = mE/50, mmE = mE%50;
          const int rE = mmE/10, cE = mmE%10;
          smh[FEATF + winE*FEATW + oc*25 + rE*5 + (cE>>1)] = (f16)eluf(fmaxf(acc[2*p], acc[2*p+1]));
        }
      }
    }
  }
  __syncthreads();

  // ---- fc1 MFMA: feat[2x416] x fc1B -> h1 f32 [2][128], elu ----
  {
    const int col = lane&15, kg = lane>>4;
    const int winc = min(col, 1);
    float* h1 = (float*)(sm + F32U);
    #pragma unroll
    for (int q2 = 0; q2 < 2; ++q2) {
      const int nt = wid + q2*4;
      f32x4 acc = {0.f, 0.f, 0.f, 0.f};
      for (int st = 0; st < 13; ++st) {
        const f16x8 a8 = *(const f16x8*)(smh + FEATF + winc*FEATW + st*32 + kg*8);
        const f16x8 b8 = *(const f16x8*)(wsF + WFC1 + ((nt*13 + st)*64 + lane)*8);
        acc = __builtin_amdgcn_mfma_f32_16x16x32_f16(a8, b8, acc, 0, 0, 0);
      }
      if (lane < 16) {
        const int n = nt*16 + col;
        const float fb = fc1b[n];
        h1[0*128 + n] = eluf(acc[0] + fb);
        h1[1*128 + n] = eluf(acc[1] + fb);
      }
    }
  }
  __syncthreads();

  // ---- fc2 -> emb -> qkv ----
  float* fregion = (float*)(sm + F32U);
  float* h1f = fregion;
  float* zpf = fregion + 256;
  float* ztf = fregion + 336;
  if (tid < 80) {
    const int w = tid/40, n = tid%40;
    const float4* hv = (const float4*)(h1f + w*128);
    const float4* wr = (const float4*)(fc2w + n*128);
    float acc = fc2b[n];
    #pragma unroll 8
    for (int c = 0; c < 32; ++c) {
      const float4 a = wr[c], x = hv[c];
      acc += a.x*x.x + a.y*x.y + a.z*x.z + a.w*x.w;
    }
    zpf[w*40 + n] = acc;
  }
  __syncthreads();
  if (tid < 80) {
    const int w = tid/40, n = tid%40;
    const float* zp = zpf + w*40;
    const float* wr = embw + n*45;
    float acc = embb[n];
    #pragma unroll 8
    for (int j = 0; j < 40; ++j) acc += wr[j]*zp[j];
    #pragma unroll
    for (int j = 0; j < 5; ++j)  acc += wr[40+j]*toh[b*5 + j];
    const float v2 = eluf(acc);
    ztf[w*40 + n] = v2;
    zt_g[(b*LSEQ + i0 + w)*40 + n] = v2;
  }
  __syncthreads();
  if (tid < 240) {
    const int which = tid/80, r = tid%80, w = r/40, n = r%40;
    const float* wm = which==0 ? wq : (which==1 ? wk : wv);
    const float* bb = which==0 ? bq : (which==1 ? bk : bv);
    const float4* wr = (const float4*)(wm + n*40);
    const float4* zv = (const float4*)(ztf + w*40);
    float acc = bb[n];
    #pragma unroll
    for (int c = 0; c < 10; ++c) {
      const float4 a = wr[c], x = zv[c];
      acc += a.x*x.x + a.y*x.y + a.z*x.z + a.w*x.w;
    }
    float* dst = which==0 ? q_g : (which==1 ? k_g : v_g);
    dst[(b*LSEQ + i0 + w)*40 + n] = acc;
  }
}

// ============ attention: one block per query row (3600), softmax without max-shift ============
__global__ __launch_bounds__(256) void attn3(
    const float* __restrict__ q_g, const float* __restrict__ k_g,
    const float* __restrict__ v_g, const float* __restrict__ zt_g,
    const int* __restrict__ dur,
    const float* __restrict__ flw1, const float* __restrict__ flb1,
    const float* __restrict__ flw2, const float* __restrict__ flb2,
    const float* __restrict__ stw1, const float* __restrict__ stb1,
    const float* __restrict__ stw2, const float* __restrict__ stb2,
    const float* __restrict__ edw1, const float* __restrict__ edb1,
    const float* __restrict__ edw2, const float* __restrict__ edb2,
    float* __restrict__ out)
{
  __shared__ __align__(16) float qrow[40];
  __shared__ __align__(16) float ztr[40];
  __shared__ __align__(16) float esm[900];
  __shared__ float red[4];
  __shared__ float part[6][40];
  __shared__ float xr[40];
  __shared__ float hb[30];

  const int tid = threadIdx.x;
  const int blk = blockIdx.x;
  const int b = blk / LSEQ, i = blk % LSEQ;
  const int durb = dur[b];
  const bool rowv = (i < durb);

  if (tid < 40){ qrow[tid] = q_g[blk*40+tid]; ztr[tid] = zt_g[blk*40+tid]; }
  __syncthreads();

  const float scale = 0.15811388300841897f;   // 1/sqrt(40)
  float lsum = 0.f;
  for (int m = tid; m < LSEQ; m += 256){
    float s;
    if (rowv && m < durb){
      const float4* kr = (const float4*)(k_g + (b*LSEQ+m)*40);
      float acc = 0.f;
      #pragma unroll
      for (int j=0;j<10;++j){ float4 kv = kr[j];
        acc += kv.x*qrow[4*j] + kv.y*qrow[4*j+1] + kv.z*qrow[4*j+2] + kv.w*qrow[4*j+3]; }
      s = acc*scale;
    } else s = -1e-12f;   // exact reference mask value
    const float e = expf(s);   // scores bounded; softmax is shift-invariant
    esm[m] = e;
    lsum += e;
  }
  // wave-level sum reduce, one barrier
  #pragma unroll
  for (int off = 32; off > 0; off >>= 1) lsum += __shfl_xor(lsum, off);
  if ((tid & 63) == 0) red[tid >> 6] = lsum;
  __syncthreads();
  const float den = red[0] + red[1] + red[2] + red[3];

  // x = (attn @ v): 6 chunks of 150 rows, 40 dims
  if (tid < 240){
    const int c = tid/40, d = tid%40;
    float acc = 0.f;
    const int m0 = c*150;
    for (int m=m0; m<m0+150; ++m) acc += esm[m]*v_g[(b*LSEQ+m)*40+d];
    part[c][d] = acc;
  }
  __syncthreads();
  if (tid < 40){
    float xv = 0.f;
    #pragma unroll
    for (int c=0;c<6;++c) xv += part[c][tid];
    xr[tid] = xv/den + ztr[tid];
  }
  __syncthreads();
  if (tid < 30){
    const int hd = tid/10, j = tid%10;
    const float* w1 = hd==0?flw1:(hd==1?stw1:edw1);
    const float* b1 = hd==0?flb1:(hd==1?stb1:edb1);
    float a = b1[j];
    #pragma unroll 8
    for (int d=0; d<40; ++d) a += w1[j*40+d]*xr[d];
    hb[tid] = eluf(a);
  }
  __syncthreads();
  if (tid < 3){
    const float* w2 = tid==0?flw2:(tid==1?stw2:edw2);
    const float* b2 = tid==0?flb2:(tid==1?stb2:edb2);
    float a = b2[0];
    #pragma unroll
    for (int j=0;j<10;++j) a += w2[j]*hb[tid*10+j];
    out[tid*NWIN + blk] = a;
  }
}

extern "C" void kernel_launch(void* const* d_in, const int* in_sizes, int n_in,
                              void* d_out, int out_size, void* d_ws, size_t ws_size,
                              hipStream_t stream) {
  const float* z    = (const float*)d_in[0];
  const float* toh  = (const float*)d_in[1];
  const int*   dur  = (const int*)d_in[2];
  const float* cw1  = (const float*)d_in[3];
  const float* cb1  = (const float*)d_in[4];
  const float* cw2  = (const float*)d_in[5];
  const float* cb2  = (const float*)d_in[6];
  const float* cw3  = (const float*)d_in[7];
  const float* cb3  = (const float*)d_in[8];
  const float* cw4  = (const float*)d_in[9];
  const float* cb4  = (const float*)d_in[10];
  const float* fc1w = (const float*)d_in[11];
  const float* fc1b = (const float*)d_in[12];
  const float* fc2w = (const float*)d_in[13];
  const float* fc2b = (const float*)d_in[14];
  const float* embw = (const float*)d_in[15];
  const float* embb = (const float*)d_in[16];
  const float* wq   = (const float*)d_in[17];
  const float* bq   = (const float*)d_in[18];
  const float* wk   = (const float*)d_in[19];
  const float* bk   = (const float*)d_in[20];
  const float* wv   = (const float*)d_in[21];
  const float* bv   = (const float*)d_in[22];
  const float* flw1 = (const float*)d_in[23];
  const float* flb1 = (const float*)d_in[24];
  const float* flw2 = (const float*)d_in[25];
  const float* flb2 = (const float*)d_in[26];
  const float* stw1 = (const float*)d_in[27];
  const float* stb1 = (const float*)d_in[28];
  const float* stw2 = (const float*)d_in[29];
  const float* stb2 = (const float*)d_in[30];
  const float* edw1 = (const float*)d_in[31];
  const float* edb1 = (const float*)d_in[32];
  const float* edw2 = (const float*)d_in[33];
  const float* edb2 = (const float*)d_in[34];

  f16*   wsF = (f16*)d_ws;
  f16*   C1  = wsF + WC1;
  f16*   TE  = wsF + WTE;
  float* wsf = (float*)d_ws;
  float* zt = wsf + WF32;
  float* q  = wsf + WF32 + 144000;
  float* k  = wsf + WF32 + 288000;
  float* v  = wsf + WF32 + 432000;

  prep_all<<<PREP_BLOCKS + CONV_BLOCKS, 256, 0, stream>>>(z, cw1, cb1, cw2, cw3, cw4, fc1w,
                                                          wsF, C1, TE);
  encoder3<<<NBLK, 256, 0, stream>>>(C1, TE, toh, cb2, cb3, cb4, wsF,
                                     fc1b, fc2w, fc2b, embw, embb,
                                     wq, bq, wk, bk, wv, bv, zt, q, k, v);
  attn3<<<NWIN, 256, 0, stream>>>(q, k, v, zt, dur,
                                  flw1, flb1, flw2, flb2,
                                  stw1, stb1, stw2, stb2,
                                  edw1, edb1, edw2, edb2,
                                  (float*)d_out);
}

// Round 7
// 99.119 us; speedup vs baseline: 1.4852x; 1.1977x over previous
//
#include <hip/hip_runtime.h>

typedef unsigned int u32;
typedef _Float16 f16;
typedef f16 f16x2 __attribute__((ext_vector_type(2)));
typedef f16 f16x4 __attribute__((ext_vector_type(4)));
typedef f16 f16x8 __attribute__((ext_vector_type(8)));
typedef float f32x4 __attribute__((ext_vector_type(4)));

#define LSEQ 900
#define BATCH 4
#define NWIN (BATCH*LSEQ)
#define WPB 2
#define NBLK (NWIN/WPB)   // 1800
#define QT 4
#define NABLK (NWIN/QT)   // 900

__device__ __forceinline__ float eluf(float x){ return x > 0.f ? x : __expf(x) - 1.f; }
#define BC2(u) __builtin_bit_cast(f16x2, (u))
#define ZERO8 __builtin_bit_cast(f16x8, (uint4{0,0,0,0}))

__device__ __forceinline__ f16x8 hmax8(f16x8 a, f16x8 b){
#if defined(__has_builtin) && __has_builtin(__builtin_elementwise_max)
  return __builtin_elementwise_max(a, b);
#else
  f16x8 r;
  #pragma unroll
  for (int i=0;i<8;++i) r[i] = a[i] > b[i] ? a[i] : b[i];
  return r;
#endif
}
__device__ __forceinline__ f16x4 hmax4(f16x4 a, f16x4 b){
#if defined(__has_builtin) && __has_builtin(__builtin_elementwise_max)
  return __builtin_elementwise_max(a, b);
#else
  f16x4 r;
  #pragma unroll
  for (int i=0;i<4;++i) r[i] = a[i] > b[i] ? a[i] : b[i];
  return r;
#endif
}

// ---- LDS map (u32 words) ----
#define P0U 0
#define P1U 4224
#define FEATU 7744
#define F32U 8160
#define SMTOT 8576
// f16 offsets / strides
#define T1F 0
#define T1W 4224
#define H2F 8448
#define H2W 3520
#define T2F 0
#define T2W 2496
#define H3F 8448
#define H3W 1600
#define T3F 0
#define T3W 1568
#define FEATF 15488
#define FEATW 416

// ---- ws f16 offsets ----
#define WB2A 0
#define WB2B 512
#define WB3  768
#define WB4  2304
#define WFC1 5376
#define WEND 58624
#define WC1  58624                 // C1: 4*900*80*4 f16 = 1152000
#define WTE  (WC1 + 1152000)       // TE: 1152000
#define WF32 ((WTE + 1152000)/2)   // f32 word offset: 1181312
// f32: zt @WF32, q @+144000, k @+288000, v @+432000

#define PREP_BLOCKS ((WEND+255)/256)        // 229
#define CONV_BLOCKS ((288000+255)/256)      // 1125

// ============ fused prep: weight packing + full-seq conv1 ============
__global__ __launch_bounds__(256) void prep_all(
    const float* __restrict__ z,
    const float* __restrict__ cw1, const float* __restrict__ cb1,
    const float* __restrict__ cw2, const float* __restrict__ cw3,
    const float* __restrict__ cw4, const float* __restrict__ fc1w,
    f16* __restrict__ wsF, f16* __restrict__ C1, f16* __restrict__ TE)
{
  const int blk = blockIdx.x;
  if (blk < PREP_BLOCKS) {
    const int g = blk*256 + threadIdx.x;
    if (g >= WEND) return;
    float val;
    if (g < 512) {
      const int l = g>>3, j = g&7;
      const int oc = l&15, c = l>>4;
      const int dr = c>>1, dc = 2*(c&1) + (j>>2), ic = j&3;
      val = (oc<8 && dc<3) ? cw2[oc*36 + ic*9 + dr*3 + dc] : 0.f;
    } else if (g < 768) {
      const int u = g-512, l = u>>2, j = u&3;
      const int oc = l&15, dc = l>>4, ic = j;
      val = (oc<8 && dc<3) ? cw2[oc*36 + ic*9 + 6 + dc] : 0.f;
    } else if (g < 2304) {
      const int u = g-768, dr = u>>9, r = u&511, l = r>>3, j = r&7;
      const int oc = l&15, dc = l>>4, ic = j;
      val = (dc<3) ? cw3[oc*72 + ic*9 + dr*3 + dc] : 0.f;
    } else if (g < 5376) {
      const int u = g-2304, v = u>>9, dr = v>>1, h = v&1;
      const int r = u&511, l = r>>3, j = r&7;
      const int oc = l&15, chunk = l>>4;
      const int dcl = chunk>>1, ic = (chunk&1)*8 + j, dc = h*2 + dcl;
      val = (dc<3) ? cw4[oc*144 + ic*9 + dr*3 + dc] : 0.f;
    } else {
      const int u = g - WFC1;
      const int j = u&7, l = (u>>3)&63, st = (u>>9)%13, nt = u/(13*512);
      const int k = st*32 + (l>>4)*8 + j, n = nt*16 + (l&15);
      val = (k<400) ? fc1w[n*400 + k] : 0.f;
    }
    wsF[g] = (f16)val;
  } else {
    const int g = (blk - PREP_BLOCKS)*256 + threadIdx.x;   // 0..287999
    if (g >= 288000) return;
    const int c = g % 80, fb2 = g / 80, f = fb2 % 900, b = fb2 / 900;
    const float* zb = z + b*72000;
    float p[3][3];
    #pragma unroll
    for (int dr = 0; dr < 3; ++dr) {
      const int r = f + dr - 1;
      #pragma unroll
      for (int dc = 0; dc < 3; ++dc) {
        const int cc = c + dc - 1;
        p[dr][dc] = (r >= 0 && r < 900 && cc >= 0 && cc < 80) ? zb[r*80+cc] : 0.f;
      }
    }
    f16x4 cf, te;
    #pragma unroll
    for (int oc = 0; oc < 4; ++oc) {
      float accf = cb1[oc], acct = cb1[oc];
      #pragma unroll
      for (int dr = 0; dr < 3; ++dr)
        #pragma unroll
        for (int dc = 0; dc < 3; ++dc) {
          const float w = cw1[oc*9 + dr*3 + dc];
          accf += w * p[dr][dc];
          if (dr) acct += w * p[dr][dc];
        }
      cf[oc] = (f16)accf; te[oc] = (f16)acct;
    }
    *(f16x4*)(C1 + g*4) = cf;
    *(f16x4*)(TE + g*4) = te;
  }
}

// ============ encoder: stage1 gather from C1/TE; stages 2-4 + fc1 on MFMA ============
__global__ __launch_bounds__(256,4) void encoder3(
    const f16* __restrict__ C1, const f16* __restrict__ TE,
    const float* __restrict__ toh,
    const float* __restrict__ cb2, const float* __restrict__ cb3, const float* __restrict__ cb4,
    const f16* __restrict__ wsF,
    const float* __restrict__ fc1b, const float* __restrict__ fc2w, const float* __restrict__ fc2b,
    const float* __restrict__ embw, const float* __restrict__ embb,
    const float* __restrict__ wq, const float* __restrict__ bq,
    const float* __restrict__ wk, const float* __restrict__ bk,
    const float* __restrict__ wv, const float* __restrict__ bv,
    float* __restrict__ zt_g, float* __restrict__ q_g,
    float* __restrict__ k_g, float* __restrict__ v_g)
{
  __shared__ __align__(16) u32 sm[SMTOT];
  f16* smh = (f16*)sm;
  const int tid = threadIdx.x, blk = blockIdx.x;
  const int lane = tid & 63, wid = tid >> 6;
  const int g0 = blk*WPB;
  const int b = g0/LSEQ, i0 = g0%LSEQ;

  // zero T1 + FEAT regions
  {
    const uint4 z4 = {0,0,0,0};
    uint4* p0 = (uint4*)(sm + P0U);
    for (int t = tid; t < 1056; t += 256) p0[t] = z4;
    uint4* pf = (uint4*)(sm + FEATU);
    for (int t = tid; t < 104; t += 256) pf[t] = z4;
  }
  __syncthreads();

  // ---- stage1: gather C1/TE rows + pool2x2 + elu -> T1 NHWC [24][44][4] ----
  {
    int e45[WPB], sv[WPB];
    #pragma unroll
    for (int w = 0; w < WPB; ++w) {
      const int i = i0 + w;
      e45[w] = min(i + 23, LSEQ) - 45;
      sv[w]  = max(i - 22, 0);
    }
    const f16* C1b = C1 + b*288000;
    const f16* TEb = TE + b*288000;
    for (int s = tid; s < 880; s += 256) {
      const int pr = s/40, pc = s%40;
      #pragma unroll
      for (int w = 0; w < WPB; ++w) {
        const int fa = e45[w] + 2*pr, fb = fa + 1;
        const int svw = sv[w];
        const f16* srcA = (fa == svw) ? TEb : C1b;
        const f16* srcB = (fb == svw) ? TEb : C1b;
        f16x8 va = *(const f16x8*)(srcA + (max(fa,0)*80 + 2*pc)*4);
        f16x8 vb = *(const f16x8*)(srcB + (max(fb,0)*80 + 2*pc)*4);
        if (fa < svw) va = ZERO8;
        if (fb < svw) vb = ZERO8;
        const f16x8 m8 = hmax8(va, vb);
        const f16x4 lo = __builtin_shufflevector(m8, m8, 0,1,2,3);
        const f16x4 hi = __builtin_shufflevector(m8, m8, 4,5,6,7);
        const f16x4 m4 = hmax4(lo, hi);
        f16x4 ov;
        #pragma unroll
        for (int oc = 0; oc < 4; ++oc) ov[oc] = (f16)eluf((float)m4[oc]);
        *(f16x4*)(smh + T1F + w*T1W + ((pr+1)*44 + pc+1)*4) = ov;
      }
    }
  }
  __syncthreads();

  // ---- stage2 MFMA: T1 -> conv(4->8); hmax -> H2 [22][20][8]; incremental addressing ----
  {
    const f16x8 B2a = *(const f16x8*)(wsF + WB2A + lane*8);
    const f16x4 B2b = *(const f16x4*)(wsF + WB2B + lane*4);
    const int oc = lane&15, chunk = lane>>4;
    const float bias2 = (oc<8) ? cb2[oc] : 0.f;
    // A-row decode (mA = t*16+oc), carried incrementally; initial t=wid -> mA<=63 < 880
    int r2 = (wid*16 + oc)/40, c2 = (wid*16 + oc)%40, winA = 0, mmA = wid*16 + oc;
    // Epilogue decode (mE = t*16+chunk*4), carried
    int rE = (wid*16 + chunk*4)/40, cE = (wid*16 + chunk*4)%40, winE = 0, mmE = wid*16 + chunk*4;
    for (int t = wid; t < 110; t += 4) {
      const f16* base = smh + T1F + winA*T1W;
      const f16* pA = base + ((r2 + (chunk>>1))*44 + c2 + 2*(chunk&1))*4;
      const f16x4 lo = *(const f16x4*)(pA);
      const f16x4 hi = *(const f16x4*)(pA + 4);
      const f16x8 a8 = __builtin_shufflevector(lo, hi, 0,1,2,3,4,5,6,7);
      f32x4 acc = {bias2, bias2, bias2, bias2};
      acc = __builtin_amdgcn_mfma_f32_16x16x32_f16(a8, B2a, acc, 0, 0, 0);
      const f16x4 a4 = *(const f16x4*)(base + ((r2+2)*44 + c2 + chunk)*4);
      acc = __builtin_amdgcn_mfma_f32_16x16x16f16(a4, B2b, acc, 0, 0, 0);
      if (oc < 8) {
        f16* h2o = smh + H2F + winE*H2W;
        h2o[(rE*20 + (cE>>1))*8 + oc] = (f16)fmaxf(acc[0], acc[1]);
        const int cE2 = cE + 2;
        const int rE2 = rE + (cE2 >= 40 ? 1 : 0);
        const int cE3 = cE2 >= 40 ? cE2 - 40 : cE2;
        h2o[(rE2*20 + (cE3>>1))*8 + oc] = (f16)fmaxf(acc[2], acc[3]);
      }
      // advance by 64 rows (= +1 row +24 cols; wrap at 880 = exactly 22 rows)
      { const int cn = c2 + 24; const int cy = cn >= 40;
        r2 += 1 + cy; c2 = cy ? cn - 40 : cn; }
      mmA += 64; if (mmA >= 880) { mmA -= 880; winA = 1; r2 -= 22; }
      { const int cn = cE + 24; const int cy = cn >= 40;
        rE += 1 + cy; cE = cy ? cn - 40 : cn; }
      mmE += 64; if (mmE >= 880) { mmE -= 880; winE = 1; rE -= 22; }
    }
  }
  __syncthreads();

  // ---- vertical max + elu: H2 -> T2 NHWC [13][24][8]; zero T2 border ----
  {
    for (int s = tid; s < 624; s += 256) {
      const int win = s/312, id = s%312;
      const int r = id/24, c = id%24;
      if (!(r>=1 && r<=11 && c>=1 && c<=20)) {
        const uint4 z4 = {0,0,0,0};
        *(uint4*)(smh + T2F + win*T2W + (r*24+c)*8) = z4;
      }
    }
    for (int s = tid; s < 1760; s += 256) {
      const int win = s/880, u = s%880;
      const int pr = u/80, rem = u%80, cp = rem/4, op = rem%4;
      const u32* h2 = (const u32*)(smh + H2F + win*H2W);
      const u32 a  = h2[((2*pr  )*20 + cp)*4 + op];
      const u32 b2 = h2[((2*pr+1)*20 + cp)*4 + op];
      const f16x2 av = BC2(a), bv = BC2(b2);
      f16x2 o;
      o.x = (f16)eluf(fmaxf((float)av.x, (float)bv.x));
      o.y = (f16)eluf(fmaxf((float)av.y, (float)bv.y));
      ((u32*)(smh + T2F + win*T2W))[((pr+1)*24 + cp+1)*4 + op] = __builtin_bit_cast(u32, o);
    }
  }
  __syncthreads();

  // ---- stage3 MFMA: T2 -> conv(8->16); hmax -> H3 [10][10][16] ----
  {
    f16x8 B3r[3];
    #pragma unroll
    for (int dr = 0; dr < 3; ++dr) B3r[dr] = *(const f16x8*)(wsF + WB3 + dr*512 + lane*8);
    const int oc = lane&15, chunk = lane>>4;
    const float bias3 = cb3[oc];
    for (int t = wid; t < 28; t += 4) {
      const int mA = t*16 + oc;
      const int winA = mA/220, mmA = mA%220;
      const int r3 = mmA/20, c3 = mmA%20;
      const f16* base = smh + T2F + min(winA,1)*T2W;
      f32x4 acc = {bias3, bias3, bias3, bias3};
      #pragma unroll
      for (int dr = 0; dr < 3; ++dr) {
        const f16x8 a8 = *(const f16x8*)(base + ((r3+dr)*24 + c3 + chunk)*8);
        acc = __builtin_amdgcn_mfma_f32_16x16x32_f16(a8, B3r[dr], acc, 0, 0, 0);
      }
      #pragma unroll
      for (int p = 0; p < 2; ++p) {
        const int mE = t*16 + chunk*4 + 2*p;
        if (mE < 440) {
          const int winE = mE/220, mmE = mE%220;
          const int rE = mmE/20, cE = mmE%20;
          if (rE < 10)
            smh[H3F + winE*H3W + (rE*10 + (cE>>1))*16 + oc] = (f16)fmaxf(acc[2*p], acc[2*p+1]);
        }
      }
    }
  }
  __syncthreads();

  // ---- vertical max + elu: H3 -> T3 NHWC [7][14][16]; zero T3 border ----
  {
    for (int s = tid; s < 196; s += 256) {
      const int win = s/98, id = s%98;
      const int r = id/14, c = id%14;
      if (!(r>=1 && r<=5 && c>=1 && c<=10)) {
        const uint4 z4 = {0,0,0,0};
        *(uint4*)(smh + T3F + win*T3W + (r*14+c)*16)     = z4;
        *(uint4*)(smh + T3F + win*T3W + (r*14+c)*16 + 8) = z4;
      }
    }
    for (int s = tid; s < 800; s += 256) {
      const int win = s/400, u = s%400;
      const int pr = u/80, rem = u%80, cp = rem/8, op = rem%8;
      const u32* h3 = (const u32*)(smh + H3F + win*H3W);
      const u32 a  = h3[((2*pr  )*10 + cp)*8 + op];
      const u32 b2 = h3[((2*pr+1)*10 + cp)*8 + op];
      const f16x2 av = BC2(a), bv = BC2(b2);
      f16x2 o;
      o.x = (f16)eluf(fmaxf((float)av.x, (float)bv.x));
      o.y = (f16)eluf(fmaxf((float)av.y, (float)bv.y));
      ((u32*)(smh + T3F + win*T3W))[((pr+1)*14 + cp+1)*8 + op] = __builtin_bit_cast(u32, o);
    }
  }
  __syncthreads();

  // ---- stage4 MFMA: T3 -> conv(16->16) + pool1x2 + elu -> feat NCHW f16[400] ----
  {
    f16x8 B4r[6];
    #pragma unroll
    for (int v = 0; v < 6; ++v) B4r[v] = *(const f16x8*)(wsF + WB4 + v*512 + lane*8);
    const int oc = lane&15, chunk = lane>>4;
    const int dcl = chunk>>1, hsel = chunk&1;
    const float bias4 = cb4[oc];
    for (int t = wid; t < 7; t += 4) {
      const int mA = t*16 + oc;
      const int winA = mA/50, mmA = mA%50;
      const int r4 = mmA/10, c4 = mmA%10;
      const f16* base = smh + T3F + min(winA,1)*T3W;
      f32x4 acc = {bias4, bias4, bias4, bias4};
      #pragma unroll
      for (int v = 0; v < 6; ++v) {
        const int dr = v>>1, h = v&1;
        const f16x8 a8 = *(const f16x8*)(base + ((r4+dr)*14 + c4 + h*2 + dcl)*16 + hsel*8);
        acc = __builtin_amdgcn_mfma_f32_16x16x32_f16(a8, B4r[v], acc, 0, 0, 0);
      }
      #pragma unroll
      for (int p = 0; p < 2; ++p) {
        const int mE = t*16 + chunk*4 + 2*p;
        if (mE < 100) {
          const int winE = mE/50, mmE = mE%50;
          const int rE = mmE/10, cE = mmE%10;
          smh[FEATF + winE*FEATW + oc*25 + rE*5 + (cE>>1)] = (f16)eluf(fmaxf(acc[2*p], acc[2*p+1]));
        }
      }
    }
  }
  __syncthreads();

  // ---- fc1 MFMA: feat[2x416] x fc1B -> h1 f32 [2][128], elu ----
  {
    const int col = lane&15, kg = lane>>4;
    const int winc = min(col, 1);
    float* h1 = (float*)(sm + F32U);
    #pragma unroll
    for (int q2 = 0; q2 < 2; ++q2) {
      const int nt = wid + q2*4;
      f32x4 acc = {0.f, 0.f, 0.f, 0.f};
      for (int st = 0; st < 13; ++st) {
        const f16x8 a8 = *(const f16x8*)(smh + FEATF + winc*FEATW + st*32 + kg*8);
        const f16x8 b8 = *(const f16x8*)(wsF + WFC1 + ((nt*13 + st)*64 + lane)*8);
        acc = __builtin_amdgcn_mfma_f32_16x16x32_f16(a8, b8, acc, 0, 0, 0);
      }
      if (lane < 16) {
        const int n = nt*16 + col;
        const float fb = fc1b[n];
        h1[0*128 + n] = eluf(acc[0] + fb);
        h1[1*128 + n] = eluf(acc[1] + fb);
      }
    }
  }
  __syncthreads();

  // ---- fc2 -> emb -> qkv ----
  float* fregion = (float*)(sm + F32U);
  float* h1f = fregion;
  float* zpf = fregion + 256;
  float* ztf = fregion + 336;
  if (tid < 80) {
    const int w = tid/40, n = tid%40;
    const float4* hv = (const float4*)(h1f + w*128);
    const float4* wr = (const float4*)(fc2w + n*128);
    float acc = fc2b[n];
    #pragma unroll 8
    for (int c = 0; c < 32; ++c) {
      const float4 a = wr[c], x = hv[c];
      acc += a.x*x.x + a.y*x.y + a.z*x.z + a.w*x.w;
    }
    zpf[w*40 + n] = acc;
  }
  __syncthreads();
  if (tid < 80) {
    const int w = tid/40, n = tid%40;
    const float* zp = zpf + w*40;
    const float* wr = embw + n*45;
    float acc = embb[n];
    #pragma unroll 8
    for (int j = 0; j < 40; ++j) acc += wr[j]*zp[j];
    #pragma unroll
    for (int j = 0; j < 5; ++j)  acc += wr[40+j]*toh[b*5 + j];
    const float v2 = eluf(acc);
    ztf[w*40 + n] = v2;
    zt_g[(b*LSEQ + i0 + w)*40 + n] = v2;
  }
  __syncthreads();
  if (tid < 240) {
    const int which = tid/80, r = tid%80, w = r/40, n = r%40;
    const float* wm = which==0 ? wq : (which==1 ? wk : wv);
    const float* bb = which==0 ? bq : (which==1 ? bk : bv);
    const float4* wr = (const float4*)(wm + n*40);
    const float4* zv = (const float4*)(ztf + w*40);
    float acc = bb[n];
    #pragma unroll
    for (int c = 0; c < 10; ++c) {
      const float4 a = wr[c], x = zv[c];
      acc += a.x*x.x + a.y*x.y + a.z*x.z + a.w*x.w;
    }
    float* dst = which==0 ? q_g : (which==1 ? k_g : v_g);
    dst[(b*LSEQ + i0 + w)*40 + n] = acc;
  }
}

// ============ attention: QT=4 query rows per block share K,V; no max-shift ============
__global__ __launch_bounds__(256) void attn4(
    const float* __restrict__ q_g, const float* __restrict__ k_g,
    const float* __restrict__ v_g, const float* __restrict__ zt_g,
    const int* __restrict__ dur,
    const float* __restrict__ flw1, const float* __restrict__ flb1,
    const float* __restrict__ flw2, const float* __restrict__ flb2,
    const float* __restrict__ stw1, const float* __restrict__ stb1,
    const float* __restrict__ stw2, const float* __restrict__ stb2,
    const float* __restrict__ edw1, const float* __restrict__ edb1,
    const float* __restrict__ edw2, const float* __restrict__ edb2,
    float* __restrict__ out)
{
  __shared__ __align__(16) float sq[QT][40];
  __shared__ __align__(16) float szt[QT][40];
  __shared__ __align__(16) float esm[QT][904];   // padded stride
  __shared__ float red[4][QT];
  __shared__ float spart[6][QT][41];             // padded: c-stride 164 words
  __shared__ __align__(16) float xr[QT][40];
  __shared__ float hb[QT][30];

  const int tid = threadIdx.x;
  const int blk = blockIdx.x;
  const int b = blk / (LSEQ/QT);
  const int q0 = (blk % (LSEQ/QT)) * QT;
  const int durb = dur[b];

  for (int t = tid; t < QT*40*2; t += 256) {
    const int which = t / (QT*40), r = t % (QT*40);
    const int q = r/40, d = r%40;
    const float v = (which ? zt_g : q_g)[(b*LSEQ + q0 + q)*40 + d];
    if (which) szt[q][d] = v; else sq[q][d] = v;
  }
  __syncthreads();

  const float scale = 0.15811388300841897f;   // 1/sqrt(40)
  float ls[QT] = {0.f, 0.f, 0.f, 0.f};
  for (int m = tid; m < LSEQ; m += 256) {
    if (m < durb) {
      float4 kv[10];
      const float4* kr4 = (const float4*)(k_g + (b*LSEQ+m)*40);
      #pragma unroll
      for (int j = 0; j < 10; ++j) kv[j] = kr4[j];
      #pragma unroll
      for (int q = 0; q < QT; ++q) {
        float e;
        if (q0 + q < durb) {
          const float4* qv = (const float4*)(&sq[q][0]);
          float acc = 0.f;
          #pragma unroll
          for (int j = 0; j < 10; ++j) {
            const float4 a = kv[j], x = qv[j];
            acc += a.x*x.x + a.y*x.y + a.z*x.z + a.w*x.w;
          }
          e = __expf(acc*scale);
        } else e = 1.f;            // exp(-1e-12) == 1.0f
        esm[q][m] = e;
        ls[q] += e;
      }
    } else {
      #pragma unroll
      for (int q = 0; q < QT; ++q) { esm[q][m] = 1.f; ls[q] += 1.f; }
    }
  }
  #pragma unroll
  for (int q = 0; q < QT; ++q) {
    float s = ls[q];
    #pragma unroll
    for (int off = 32; off > 0; off >>= 1) s += __shfl_xor(s, off);
    if ((tid & 63) == 0) red[tid >> 6][q] = s;
  }
  __syncthreads();

  // PV: 240 threads = (chunk c of 150 rows, dim d); each accumulates all QT rows
  if (tid < 240) {
    const int c = tid/40, d = tid%40;
    const float* vb = v_g + (b*LSEQ + c*150)*40 + d;
    const int m0 = c*150;
    float a0=0.f, a1=0.f, a2=0.f, a3=0.f;
    for (int mm = 0; mm < 150; ++mm) {
      const float vv = vb[mm*40];
      a0 += esm[0][m0+mm]*vv; a1 += esm[1][m0+mm]*vv;
      a2 += esm[2][m0+mm]*vv; a3 += esm[3][m0+mm]*vv;
    }
    spart[c][0][d] = a0; spart[c][1][d] = a1;
    spart[c][2][d] = a2; spart[c][3][d] = a3;
  }
  __syncthreads();

  if (tid < QT*40) {
    const int q = tid/40, d = tid%40;
    const float den = red[0][q] + red[1][q] + red[2][q] + red[3][q];
    float xv = 0.f;
    #pragma unroll
    for (int c = 0; c < 6; ++c) xv += spart[c][q][d];
    xr[q][d] = xv/den + szt[q][d];
  }
  __syncthreads();

  if (tid < QT*30) {
    const int q = tid/30, rr = tid%30, hd = rr/10, j = rr%10;
    const float* w1 = hd==0?flw1:(hd==1?stw1:edw1);
    const float* b1 = hd==0?flb1:(hd==1?stb1:edb1);
    float a = b1[j];
    #pragma unroll 8
    for (int d = 0; d < 40; ++d) a += w1[j*40+d]*xr[q][d];
    hb[q][hd*10+j] = eluf(a);
  }
  __syncthreads();
  if (tid < QT*3) {
    const int q = tid/3, hd = tid%3;
    const float* w2 = hd==0?flw2:(hd==1?stw2:edw2);
    const float* b2 = hd==0?flb2:(hd==1?stb2:edb2);
    float a = b2[0];
    #pragma unroll
    for (int j = 0; j < 10; ++j) a += w2[j]*hb[q][hd*10+j];
    out[hd*NWIN + b*LSEQ + q0 + q] = a;
  }
}

extern "C" void kernel_launch(void* const* d_in, const int* in_sizes, int n_in,
                              void* d_out, int out_size, void* d_ws, size_t ws_size,
                              hipStream_t stream) {
  const float* z    = (const float*)d_in[0];
  const float* toh  = (const float*)d_in[1];
  const int*   dur  = (const int*)d_in[2];
  const float* cw1  = (const float*)d_in[3];
  const float* cb1  = (const float*)d_in[4];
  const float* cw2  = (const float*)d_in[5];
  const float* cb2  = (const float*)d_in[6];
  const float* cw3  = (const float*)d_in[7];
  const float* cb3  = (const float*)d_in[8];
  const float* cw4  = (const float*)d_in[9];
  const float* cb4  = (const float*)d_in[10];
  const float* fc1w = (const float*)d_in[11];
  const float* fc1b = (const float*)d_in[12];
  const float* fc2w = (const float*)d_in[13];
  const float* fc2b = (const float*)d_in[14];
  const float* embw = (const float*)d_in[15];
  const float* embb = (const float*)d_in[16];
  const float* wq   = (const float*)d_in[17];
  const float* bq   = (const float*)d_in[18];
  const float* wk   = (const float*)d_in[19];
  const float* bk   = (const float*)d_in[20];
  const float* wv   = (const float*)d_in[21];
  const float* bv   = (const float*)d_in[22];
  const float* flw1 = (const float*)d_in[23];
  const float* flb1 = (const float*)d_in[24];
  const float* flw2 = (const float*)d_in[25];
  const float* flb2 = (const float*)d_in[26];
  const float* stw1 = (const float*)d_in[27];
  const float* stb1 = (const float*)d_in[28];
  const float* stw2 = (const float*)d_in[29];
  const float* stb2 = (const float*)d_in[30];
  const float* edw1 = (const float*)d_in[31];
  const float* edb1 = (const float*)d_in[32];
  const float* edw2 = (const float*)d_in[33];
  const float* edb2 = (const float*)d_in[34];

  f16*   wsF = (f16*)d_ws;
  f16*   C1  = wsF + WC1;
  f16*   TE  = wsF + WTE;
  float* wsf = (float*)d_ws;
  float* zt = wsf + WF32;
  float* q  = wsf + WF32 + 144000;
  float* k  = wsf + WF32 + 288000;
  float* v  = wsf + WF32 + 432000;

  prep_all<<<PREP_BLOCKS + CONV_BLOCKS, 256, 0, stream>>>(z, cw1, cb1, cw2, cw3, cw4, fc1w,
                                                          wsF, C1, TE);
  encoder3<<<NBLK, 256, 0, stream>>>(C1, TE, toh, cb2, cb3, cb4, wsF,
                                     fc1b, fc2w, fc2b, embw, embb,
                                     wq, bq, wk, bk, wv, bv, zt, q, k, v);
  attn4<<<NABLK, 256, 0, stream>>>(q, k, v, zt, dur,
                                   flw1, flb1, flw2, flb2,
                                   stw1, stb1, stw2, stb2,
                                   edw1, edb1, edw2, edb2,
                                   (float*)d_out);
}

// Round 8
// 88.094 us; speedup vs baseline: 1.6711x; 1.1251x over previous
//
#include <hip/hip_runtime.h>

typedef unsigned int u32;
typedef _Float16 f16;
typedef f16 f16x2 __attribute__((ext_vector_type(2)));
typedef f16 f16x4 __attribute__((ext_vector_type(4)));
typedef f16 f16x8 __attribute__((ext_vector_type(8)));
typedef float f32x4 __attribute__((ext_vector_type(4)));

#define LSEQ 900
#define BATCH 4
#define NWIN (BATCH*LSEQ)
#define NBLK NWIN         // WPB=1 -> 3600 blocks
#define QT 4
#define NABLK (NWIN/QT)   // 900

__device__ __forceinline__ float eluf(float x){ return x > 0.f ? x : __expf(x) - 1.f; }
#define BC2(u) __builtin_bit_cast(f16x2, (u))
#define ZERO8 __builtin_bit_cast(f16x8, (uint4{0,0,0,0}))

__device__ __forceinline__ f16x8 hmax8(f16x8 a, f16x8 b){
#if defined(__has_builtin) && __has_builtin(__builtin_elementwise_max)
  return __builtin_elementwise_max(a, b);
#else
  f16x8 r;
  #pragma unroll
  for (int i=0;i<8;++i) r[i] = a[i] > b[i] ? a[i] : b[i];
  return r;
#endif
}
__device__ __forceinline__ f16x4 hmax4(f16x4 a, f16x4 b){
#if defined(__has_builtin) && __has_builtin(__builtin_elementwise_max)
  return __builtin_elementwise_max(a, b);
#else
  f16x4 r;
  #pragma unroll
  for (int i=0;i<4;++i) r[i] = a[i] > b[i] ? a[i] : b[i];
  return r;
#endif
}

// ---- LDS map (u32 words), WPB=1 ----
// P0 [0,2112): T1 [24][44][4] f16 -> later T2 [13][24][8] (1248) -> T3 [7][14][16] (784)
// P1 [2112,3872): H2 [22][20][8] f16 (1760) -> H3 [10][10][16] (800)
// FEAT [3872,4080): 416 f16 (tail zeros = fc1 K-pad)
// F32 [4080,4288): h1 128 + zp 40 + zt 40
#define P0U 0
#define P1U 2112
#define FEATU 3872
#define F32U 4080
#define SMTOT 4288
// f16 offsets
#define T1F 0
#define H2F 4224
#define T2F 0
#define H3F 4224
#define T3F 0
#define FEATF 7744

// ---- ws f16 offsets ----
#define WB2A 0
#define WB2B 512
#define WB3  768
#define WB4  2304
#define WFC1 5376
#define WEND 58624
#define WC1  58624                 // C1: 4*900*80*4 f16 = 1152000
#define WTE  (WC1 + 1152000)       // TE: 1152000
#define WF32 ((WTE + 1152000)/2)   // f32 word offset: 1181312
// f32: zt @WF32, q @+144000, k @+288000, v @+432000

#define PREP_BLOCKS ((WEND+255)/256)        // 229
#define CONV_BLOCKS ((288000+255)/256)      // 1125

// ============ fused prep: weight packing + full-seq conv1 ============
__global__ __launch_bounds__(256) void prep_all(
    const float* __restrict__ z,
    const float* __restrict__ cw1, const float* __restrict__ cb1,
    const float* __restrict__ cw2, const float* __restrict__ cw3,
    const float* __restrict__ cw4, const float* __restrict__ fc1w,
    f16* __restrict__ wsF, f16* __restrict__ C1, f16* __restrict__ TE)
{
  const int blk = blockIdx.x;
  if (blk < PREP_BLOCKS) {
    const int g = blk*256 + threadIdx.x;
    if (g >= WEND) return;
    float val;
    if (g < 512) {
      const int l = g>>3, j = g&7;
      const int oc = l&15, c = l>>4;
      const int dr = c>>1, dc = 2*(c&1) + (j>>2), ic = j&3;
      val = (oc<8 && dc<3) ? cw2[oc*36 + ic*9 + dr*3 + dc] : 0.f;
    } else if (g < 768) {
      const int u = g-512, l = u>>2, j = u&3;
      const int oc = l&15, dc = l>>4, ic = j;
      val = (oc<8 && dc<3) ? cw2[oc*36 + ic*9 + 6 + dc] : 0.f;
    } else if (g < 2304) {
      const int u = g-768, dr = u>>9, r = u&511, l = r>>3, j = r&7;
      const int oc = l&15, dc = l>>4, ic = j;
      val = (dc<3) ? cw3[oc*72 + ic*9 + dr*3 + dc] : 0.f;
    } else if (g < 5376) {
      const int u = g-2304, v = u>>9, dr = v>>1, h = v&1;
      const int r = u&511, l = r>>3, j = r&7;
      const int oc = l&15, chunk = l>>4;
      const int dcl = chunk>>1, ic = (chunk&1)*8 + j, dc = h*2 + dcl;
      val = (dc<3) ? cw4[oc*144 + ic*9 + dr*3 + dc] : 0.f;
    } else {
      const int u = g - WFC1;
      const int j = u&7, l = (u>>3)&63, st = (u>>9)%13, nt = u/(13*512);
      const int k = st*32 + (l>>4)*8 + j, n = nt*16 + (l&15);
      val = (k<400) ? fc1w[n*400 + k] : 0.f;
    }
    wsF[g] = (f16)val;
  } else {
    const int g = (blk - PREP_BLOCKS)*256 + threadIdx.x;   // 0..287999
    if (g >= 288000) return;
    const int c = g % 80, fb2 = g / 80, f = fb2 % 900, b = fb2 / 900;
    const float* zb = z + b*72000;
    float p[3][3];
    #pragma unroll
    for (int dr = 0; dr < 3; ++dr) {
      const int r = f + dr - 1;
      #pragma unroll
      for (int dc = 0; dc < 3; ++dc) {
        const int cc = c + dc - 1;
        p[dr][dc] = (r >= 0 && r < 900 && cc >= 0 && cc < 80) ? zb[r*80+cc] : 0.f;
      }
    }
    f16x4 cf, te;
    #pragma unroll
    for (int oc = 0; oc < 4; ++oc) {
      float accf = cb1[oc], acct = cb1[oc];
      #pragma unroll
      for (int dr = 0; dr < 3; ++dr)
        #pragma unroll
        for (int dc = 0; dc < 3; ++dc) {
          const float w = cw1[oc*9 + dr*3 + dc];
          accf += w * p[dr][dc];
          if (dr) acct += w * p[dr][dc];
        }
      cf[oc] = (f16)accf; te[oc] = (f16)acct;
    }
    *(f16x4*)(C1 + g*4) = cf;
    *(f16x4*)(TE + g*4) = te;
  }
}

// ============ encoder WPB=1: stage1 gather; stages 2-4 + fc1 MFMA; small LDS ============
__global__ __launch_bounds__(256,6) void encoder4(
    const f16* __restrict__ C1, const f16* __restrict__ TE,
    const float* __restrict__ toh,
    const float* __restrict__ cb2, const float* __restrict__ cb3, const float* __restrict__ cb4,
    const f16* __restrict__ wsF,
    const float* __restrict__ fc1b, const float* __restrict__ fc2w, const float* __restrict__ fc2b,
    const float* __restrict__ embw, const float* __restrict__ embb,
    const float* __restrict__ wq, const float* __restrict__ bq,
    const float* __restrict__ wk, const float* __restrict__ bk,
    const float* __restrict__ wv, const float* __restrict__ bv,
    float* __restrict__ zt_g, float* __restrict__ q_g,
    float* __restrict__ k_g, float* __restrict__ v_g)
{
  __shared__ __align__(16) u32 sm[SMTOT];
  f16* smh = (f16*)sm;
  const int tid = threadIdx.x, blk = blockIdx.x;
  const int lane = tid & 63, wid = tid >> 6;
  const int b = blk/LSEQ, i0 = blk%LSEQ;

  // zero P0 (T1 incl. borders) + FEAT
  {
    const uint4 z4 = {0,0,0,0};
    uint4* p0 = (uint4*)(sm + P0U);
    for (int t = tid; t < 528; t += 256) p0[t] = z4;
    uint4* pf = (uint4*)(sm + FEATU);
    if (tid < 52) pf[tid] = z4;
  }
  __syncthreads();

  // ---- stage1: gather C1/TE rows + pool2x2 + elu -> T1 NHWC [24][44][4] ----
  {
    const int e45 = min(i0 + 23, LSEQ) - 45;
    const int sv  = max(i0 - 22, 0);
    const f16* C1b = C1 + b*288000;
    const f16* TEb = TE + b*288000;
    for (int s = tid; s < 880; s += 256) {
      const int pr = s/40, pc = s%40;
      const int fa = e45 + 2*pr, fb = fa + 1;
      const f16* srcA = (fa == sv) ? TEb : C1b;
      const f16* srcB = (fb == sv) ? TEb : C1b;
      f16x8 va = *(const f16x8*)(srcA + (max(fa,0)*80 + 2*pc)*4);
      f16x8 vb = *(const f16x8*)(srcB + (max(fb,0)*80 + 2*pc)*4);
      if (fa < sv) va = ZERO8;
      if (fb < sv) vb = ZERO8;
      const f16x8 m8 = hmax8(va, vb);
      const f16x4 lo = __builtin_shufflevector(m8, m8, 0,1,2,3);
      const f16x4 hi = __builtin_shufflevector(m8, m8, 4,5,6,7);
      const f16x4 m4 = hmax4(lo, hi);
      f16x4 ov;
      #pragma unroll
      for (int oc = 0; oc < 4; ++oc) ov[oc] = (f16)eluf((float)m4[oc]);
      *(f16x4*)(smh + T1F + ((pr+1)*44 + pc+1)*4) = ov;
    }
  }
  __syncthreads();

  // ---- stage2 MFMA: T1 -> conv(4->8); hmax -> H2 [22][20][8]; incremental addressing ----
  {
    const f16x8 B2a = *(const f16x8*)(wsF + WB2A + lane*8);
    const f16x4 B2b = *(const f16x4*)(wsF + WB2B + lane*4);
    const int oc = lane&15, chunk = lane>>4;
    const float bias2 = (oc<8) ? cb2[oc] : 0.f;
    int r2 = (wid*16 + oc)/40, c2 = (wid*16 + oc)%40;
    int rE = (wid*16 + chunk*4)/40, cE = (wid*16 + chunk*4)%40;
    for (int t = wid; t < 55; t += 4) {
      const f16* base = smh + T1F;
      const f16* pA = base + ((r2 + (chunk>>1))*44 + c2 + 2*(chunk&1))*4;
      const f16x4 lo = *(const f16x4*)(pA);
      const f16x4 hi = *(const f16x4*)(pA + 4);
      const f16x8 a8 = __builtin_shufflevector(lo, hi, 0,1,2,3,4,5,6,7);
      f32x4 acc = {bias2, bias2, bias2, bias2};
      acc = __builtin_amdgcn_mfma_f32_16x16x32_f16(a8, B2a, acc, 0, 0, 0);
      const f16x4 a4 = *(const f16x4*)(base + ((r2+2)*44 + c2 + chunk)*4);
      acc = __builtin_amdgcn_mfma_f32_16x16x16f16(a4, B2b, acc, 0, 0, 0);
      if (oc < 8) {
        f16* h2o = smh + H2F;
        h2o[(rE*20 + (cE>>1))*8 + oc] = (f16)fmaxf(acc[0], acc[1]);
        const int cE2 = cE + 2;
        const int rE2 = rE + (cE2 >= 40 ? 1 : 0);
        const int cE3 = cE2 >= 40 ? cE2 - 40 : cE2;
        h2o[(rE2*20 + (cE3>>1))*8 + oc] = (f16)fmaxf(acc[2], acc[3]);
      }
      // advance by 64 positions = +1 row +24 cols (40-col space)
      { const int cn = c2 + 24; const int cy = cn >= 40;
        r2 += 1 + cy; c2 = cy ? cn - 40 : cn; }
      { const int cn = cE + 24; const int cy = cn >= 40;
        rE += 1 + cy; cE = cy ? cn - 40 : cn; }
    }
  }
  __syncthreads();

  // ---- vertical max + elu: H2 -> T2 NHWC [13][24][8]; zero T2 border ----
  {
    for (int s = tid; s < 312; s += 256) {
      const int r = s/24, c = s%24;
      if (!(r>=1 && r<=11 && c>=1 && c<=20)) {
        const uint4 z4 = {0,0,0,0};
        *(uint4*)(smh + T2F + (r*24+c)*8) = z4;
      }
    }
    for (int s = tid; s < 880; s += 256) {
      const int pr = s/80, rem = s%80, cp = rem/4, op = rem%4;
      const u32* h2 = (const u32*)(smh + H2F);
      const u32 a  = h2[((2*pr  )*20 + cp)*4 + op];
      const u32 b2 = h2[((2*pr+1)*20 + cp)*4 + op];
      const f16x2 av = BC2(a), bv = BC2(b2);
      f16x2 o;
      o.x = (f16)eluf(fmaxf((float)av.x, (float)bv.x));
      o.y = (f16)eluf(fmaxf((float)av.y, (float)bv.y));
      ((u32*)(smh + T2F))[((pr+1)*24 + cp+1)*4 + op] = __builtin_bit_cast(u32, o);
    }
  }
  __syncthreads();

  // ---- stage3 MFMA: T2 -> conv(8->16); hmax -> H3 [10][10][16] ----
  {
    f16x8 B3r[3];
    #pragma unroll
    for (int dr = 0; dr < 3; ++dr) B3r[dr] = *(const f16x8*)(wsF + WB3 + dr*512 + lane*8);
    const int oc = lane&15, chunk = lane>>4;
    const float bias3 = cb3[oc];
    for (int t = wid; t < 14; t += 4) {
      const int mA = t*16 + oc;          // may reach 223 > 219: reads junk rows, outputs masked
      const int r3 = mA/20, c3 = mA%20;
      const f16* base = smh + T2F;
      f32x4 acc = {bias3, bias3, bias3, bias3};
      #pragma unroll
      for (int dr = 0; dr < 3; ++dr) {
        const f16x8 a8 = *(const f16x8*)(base + ((r3+dr)*24 + c3 + chunk)*8);
        acc = __builtin_amdgcn_mfma_f32_16x16x32_f16(a8, B3r[dr], acc, 0, 0, 0);
      }
      #pragma unroll
      for (int p = 0; p < 2; ++p) {
        const int mE = t*16 + chunk*4 + 2*p;
        if (mE < 220) {
          const int rE = mE/20, cE = mE%20;
          if (rE < 10)
            smh[H3F + (rE*10 + (cE>>1))*16 + oc] = (f16)fmaxf(acc[2*p], acc[2*p+1]);
        }
      }
    }
  }
  __syncthreads();

  // ---- vertical max + elu: H3 -> T3 NHWC [7][14][16]; zero T3 border ----
  {
    for (int s = tid; s < 98; s += 256) {
      const int r = s/14, c = s%14;
      if (!(r>=1 && r<=5 && c>=1 && c<=10)) {
        const uint4 z4 = {0,0,0,0};
        *(uint4*)(smh + T3F + (r*14+c)*16)     = z4;
        *(uint4*)(smh + T3F + (r*14+c)*16 + 8) = z4;
      }
    }
    for (int s = tid; s < 400; s += 256) {
      const int pr = s/80, rem = s%80, cp = rem/8, op = rem%8;
      const u32* h3 = (const u32*)(smh + H3F);
      const u32 a  = h3[((2*pr  )*10 + cp)*8 + op];
      const u32 b2 = h3[((2*pr+1)*10 + cp)*8 + op];
      const f16x2 av = BC2(a), bv = BC2(b2);
      f16x2 o;
      o.x = (f16)eluf(fmaxf((float)av.x, (float)bv.x));
      o.y = (f16)eluf(fmaxf((float)av.y, (float)bv.y));
      ((u32*)(smh + T3F))[((pr+1)*14 + cp+1)*8 + op] = __builtin_bit_cast(u32, o);
    }
  }
  __syncthreads();

  // ---- stage4 MFMA: T3 -> conv(16->16) + pool1x2 + elu -> feat NCHW f16[400] in LDS ----
  {
    f16x8 B4r[6];
    #pragma unroll
    for (int v = 0; v < 6; ++v) B4r[v] = *(const f16x8*)(wsF + WB4 + v*512 + lane*8);
    const int oc = lane&15, chunk = lane>>4;
    const int dcl = chunk>>1, hsel = chunk&1;
    const float bias4 = cb4[oc];
    for (int t = wid; t < 4; t += 4) {
      const int mA = t*16 + oc;
      const int mmA = mA < 50 ? mA : mA - 50;
      const int r4 = mmA/10, c4 = mmA%10;
      const f16* base = smh + T3F;
      f32x4 acc = {bias4, bias4, bias4, bias4};
      #pragma unroll
      for (int v = 0; v < 6; ++v) {
        const int dr = v>>1, h = v&1;
        const f16x8 a8 = *(const f16x8*)(base + ((r4+dr)*14 + c4 + h*2 + dcl)*16 + hsel*8);
        acc = __builtin_amdgcn_mfma_f32_16x16x32_f16(a8, B4r[v], acc, 0, 0, 0);
      }
      #pragma unroll
      for (int p = 0; p < 2; ++p) {
        const int mE = t*16 + chunk*4 + 2*p;
        if (mE < 50) {
          const int rE = mE/10, cE = mE%10;
          smh[FEATF + oc*25 + rE*5 + (cE>>1)] = (f16)eluf(fmaxf(acc[2*p], acc[2*p+1]));
        }
      }
    }
  }
  __syncthreads();

  // ---- fc1 MFMA: feat[416] x fc1B -> h1 f32[128], elu ----
  {
    float* h1 = (float*)(sm + F32U);
    #pragma unroll
    for (int q2 = 0; q2 < 2; ++q2) {
      const int nt = wid + q2*4;
      f32x4 acc = {0.f, 0.f, 0.f, 0.f};
      for (int st = 0; st < 13; ++st) {
        const f16x8 a8 = *(const f16x8*)(smh + FEATF + st*32 + (lane>>4)*8);
        const f16x8 b8 = *(const f16x8*)(wsF + WFC1 + ((nt*13 + st)*64 + lane)*8);
        acc = __builtin_amdgcn_mfma_f32_16x16x32_f16(a8, b8, acc, 0, 0, 0);
      }
      if (lane < 16) {
        const int n = nt*16 + lane;
        h1[n] = eluf(acc[0] + fc1b[n]);
      }
    }
  }
  __syncthreads();

  // ---- fc2 -> emb -> qkv ----
  float* fregion = (float*)(sm + F32U);
  float* h1f = fregion;
  float* zpf = fregion + 128;
  float* ztf = fregion + 168;
  if (tid < 40) {
    const int n = tid;
    const float4* hv = (const float4*)h1f;
    const float4* wr = (const float4*)(fc2w + n*128);
    float acc = fc2b[n];
    #pragma unroll 8
    for (int c = 0; c < 32; ++c) {
      const float4 a = wr[c], x = hv[c];
      acc += a.x*x.x + a.y*x.y + a.z*x.z + a.w*x.w;
    }
    zpf[n] = acc;
  }
  __syncthreads();
  if (tid < 40) {
    const int n = tid;
    const float* wr = embw + n*45;
    float acc = embb[n];
    #pragma unroll 8
    for (int j = 0; j < 40; ++j) acc += wr[j]*zpf[j];
    #pragma unroll
    for (int j = 0; j < 5; ++j)  acc += wr[40+j]*toh[b*5 + j];
    const float v2 = eluf(acc);
    ztf[n] = v2;
    zt_g[(b*LSEQ + i0)*40 + n] = v2;
  }
  __syncthreads();
  if (tid < 120) {
    const int which = tid/40, n = tid%40;
    const float* wm = which==0 ? wq : (which==1 ? wk : wv);
    const float* bb = which==0 ? bq : (which==1 ? bk : bv);
    const float4* wr = (const float4*)(wm + n*40);
    const float4* zv = (const float4*)ztf;
    float acc = bb[n];
    #pragma unroll
    for (int c = 0; c < 10; ++c) {
      const float4 a = wr[c], x = zv[c];
      acc += a.x*x.x + a.y*x.y + a.z*x.z + a.w*x.w;
    }
    float* dst = which==0 ? q_g : (which==1 ? k_g : v_g);
    dst[(b*LSEQ + i0)*40 + n] = acc;
  }
}

// ============ attention: QT=4 query rows per block share K,V; no max-shift ============
__global__ __launch_bounds__(256) void attn4(
    const float* __restrict__ q_g, const float* __restrict__ k_g,
    const float* __restrict__ v_g, const float* __restrict__ zt_g,
    const int* __restrict__ dur,
    const float* __restrict__ flw1, const float* __restrict__ flb1,
    const float* __restrict__ flw2, const float* __restrict__ flb2,
    const float* __restrict__ stw1, const float* __restrict__ stb1,
    const float* __restrict__ stw2, const float* __restrict__ stb2,
    const float* __restrict__ edw1, const float* __restrict__ edb1,
    const float* __restrict__ edw2, const float* __restrict__ edb2,
    float* __restrict__ out)
{
  __shared__ __align__(16) float sq[QT][40];
  __shared__ __align__(16) float szt[QT][40];
  __shared__ __align__(16) float esm[QT][904];
  __shared__ float red[4][QT];
  __shared__ float spart[6][QT][41];
  __shared__ __align__(16) float xr[QT][40];
  __shared__ float hb[QT][30];

  const int tid = threadIdx.x;
  const int blk = blockIdx.x;
  const int b = blk / (LSEQ/QT);
  const int q0 = (blk % (LSEQ/QT)) * QT;
  const int durb = dur[b];

  for (int t = tid; t < QT*40*2; t += 256) {
    const int which = t / (QT*40), r = t % (QT*40);
    const int q = r/40, d = r%40;
    const float v = (which ? zt_g : q_g)[(b*LSEQ + q0 + q)*40 + d];
    if (which) szt[q][d] = v; else sq[q][d] = v;
  }
  __syncthreads();

  const float scale = 0.15811388300841897f;   // 1/sqrt(40)
  float ls[QT] = {0.f, 0.f, 0.f, 0.f};
  for (int m = tid; m < LSEQ; m += 256) {
    if (m < durb) {
      float4 kv[10];
      const float4* kr4 = (const float4*)(k_g + (b*LSEQ+m)*40);
      #pragma unroll
      for (int j = 0; j < 10; ++j) kv[j] = kr4[j];
      #pragma unroll
      for (int q = 0; q < QT; ++q) {
        float e;
        if (q0 + q < durb) {
          const float4* qv = (const float4*)(&sq[q][0]);
          float acc = 0.f;
          #pragma unroll
          for (int j = 0; j < 10; ++j) {
            const float4 a = kv[j], x = qv[j];
            acc += a.x*x.x + a.y*x.y + a.z*x.z + a.w*x.w;
          }
          e = __expf(acc*scale);
        } else e = 1.f;
        esm[q][m] = e;
        ls[q] += e;
      }
    } else {
      #pragma unroll
      for (int q = 0; q < QT; ++q) { esm[q][m] = 1.f; ls[q] += 1.f; }
    }
  }
  #pragma unroll
  for (int q = 0; q < QT; ++q) {
    float s = ls[q];
    #pragma unroll
    for (int off = 32; off > 0; off >>= 1) s += __shfl_xor(s, off);
    if ((tid & 63) == 0) red[tid >> 6][q] = s;
  }
  __syncthreads();

  if (tid < 240) {
    const int c = tid/40, d = tid%40;
    const float* vb = v_g + (b*LSEQ + c*150)*40 + d;
    const int m0 = c*150;
    float a0=0.f, a1=0.f, a2=0.f, a3=0.f;
    for (int mm = 0; mm < 150; ++mm) {
      const float vv = vb[mm*40];
      a0 += esm[0][m0+mm]*vv; a1 += esm[1][m0+mm]*vv;
      a2 += esm[2][m0+mm]*vv; a3 += esm[3][m0+mm]*vv;
    }
    spart[c][0][d] = a0; spart[c][1][d] = a1;
    spart[c][2][d] = a2; spart[c][3][d] = a3;
  }
  __syncthreads();

  if (tid < QT*40) {
    const int q = tid/40, d = tid%40;
    const float den = red[0][q] + red[1][q] + red[2][q] + red[3][q];
    float xv = 0.f;
    #pragma unroll
    for (int c = 0; c < 6; ++c) xv += spart[c][q][d];
    xr[q][d] = xv/den + szt[q][d];
  }
  __syncthreads();

  if (tid < QT*30) {
    const int q = tid/30, rr = tid%30, hd = rr/10, j = rr%10;
    const float* w1 = hd==0?flw1:(hd==1?stw1:edw1);
    const float* b1 = hd==0?flb1:(hd==1?stb1:edb1);
    float a = b1[j];
    #pragma unroll 8
    for (int d = 0; d < 40; ++d) a += w1[j*40+d]*xr[q][d];
    hb[q][hd*10+j] = eluf(a);
  }
  __syncthreads();
  if (tid < QT*3) {
    const int q = tid/3, hd = tid%3;
    const float* w2 = hd==0?flw2:(hd==1?stw2:edw2);
    const float* b2 = hd==0?flb2:(hd==1?stb2:edb2);
    float a = b2[0];
    #pragma unroll
    for (int j = 0; j < 10; ++j) a += w2[j]*hb[q][hd*10+j];
    out[hd*NWIN + b*LSEQ + q0 + q] = a;
  }
}

extern "C" void kernel_launch(void* const* d_in, const int* in_sizes, int n_in,
                              void* d_out, int out_size, void* d_ws, size_t ws_size,
                              hipStream_t stream) {
  const float* z    = (const float*)d_in[0];
  const float* toh  = (const float*)d_in[1];
  const int*   dur  = (const int*)d_in[2];
  const float* cw1  = (const float*)d_in[3];
  const float* cb1  = (const float*)d_in[4];
  const float* cw2  = (const float*)d_in[5];
  const float* cb2  = (const float*)d_in[6];
  const float* cw3  = (const float*)d_in[7];
  const float* cb3  = (const float*)d_in[8];
  const float* cw4  = (const float*)d_in[9];
  const float* cb4  = (const float*)d_in[10];
  const float* fc1w = (const float*)d_in[11];
  const float* fc1b = (const float*)d_in[12];
  const float* fc2w = (const float*)d_in[13];
  const float* fc2b = (const float*)d_in[14];
  const float* embw = (const float*)d_in[15];
  const float* embb = (const float*)d_in[16];
  const float* wq   = (const float*)d_in[17];
  const float* bq   = (const float*)d_in[18];
  const float* wk   = (const float*)d_in[19];
  const float* bk   = (const float*)d_in[20];
  const float* wv   = (const float*)d_in[21];
  const float* bv   = (const float*)d_in[22];
  const float* flw1 = (const float*)d_in[23];
  const float* flb1 = (const float*)d_in[24];
  const float* flw2 = (const float*)d_in[25];
  const float* flb2 = (const float*)d_in[26];
  const float* stw1 = (const float*)d_in[27];
  const float* stb1 = (const float*)d_in[28];
  const float* stw2 = (const float*)d_in[29];
  const float* stb2 = (const float*)d_in[30];
  const float* edw1 = (const float*)d_in[31];
  const float* edb1 = (const float*)d_in[32];
  const float* edw2 = (const float*)d_in[33];
  const float* edb2 = (const float*)d_in[34];

  f16*   wsF = (f16*)d_ws;
  f16*   C1  = wsF + WC1;
  f16*   TE  = wsF + WTE;
  float* wsf = (float*)d_ws;
  float* zt = wsf + WF32;
  float* q  = wsf + WF32 + 144000;
  float* k  = wsf + WF32 + 288000;
  float* v  = wsf + WF32 + 432000;

  prep_all<<<PREP_BLOCKS + CONV_BLOCKS, 256, 0, stream>>>(z, cw1, cb1, cw2, cw3, cw4, fc1w,
                                                          wsF, C1, TE);
  encoder4<<<NBLK, 256, 0, stream>>>(C1, TE, toh, cb2, cb3, cb4, wsF,
                                     fc1b, fc2w, fc2b, embw, embb,
                                     wq, bq, wk, bk, wv, bv, zt, q, k, v);
  attn4<<<NABLK, 256, 0, stream>>>(q, k, v, zt, dur,
                                   flw1, flb1, flw2, flb2,
                                   stw1, stb1, stw2, stb2,
                                   edw1, edb1, edw2, edb2,
                                   (float*)d_out);
}